// Round 8
// baseline (3675.097 us; speedup 1.0000x reference)
//
#include <hip/hip_runtime.h>
#include <math.h>

#define NPTS 4096
#define HDIM 128
#define KNN 10
#define NSPLIT 4
#define SLOTS 12
#define GC 16
#define NCELL 4096   // GC^3

typedef __attribute__((ext_vector_type(4))) float f32x4;
typedef __attribute__((ext_vector_type(4))) int   i32x4;
typedef __attribute__((ext_vector_type(8))) short s16x8;

__device__ __forceinline__ float relu_f(float x) { return x > 0.f ? x : 0.f; }
__device__ __forceinline__ float med3_f(float a, float b, float c) {
    return __builtin_amdgcn_fmed3f(a, b, c);
}
__device__ __forceinline__ unsigned bf16_rne(float f) {
    unsigned u = __float_as_uint(f);
    return (u + 0x7fffu + ((u >> 16) & 1u)) >> 16;
}
__device__ __forceinline__ float bf2f(unsigned h) { return __uint_as_float(h << 16); }

__device__ __forceinline__ int cell_coord(float v, float mn, float iw) {
    int c = (int)((v - mn) * iw);
    return min(GC - 1, max(0, c));
}

// ---------------------------------------------------------------- bbox per graph
__global__ __launch_bounds__(256) void bbox_kernel(const float* __restrict__ pos,
                                                   float* __restrict__ bboxb)
{
    __shared__ float smn[3][4], smx[3][4];
    const int g = blockIdx.x;
    const float* pb = pos + (size_t)g * NPTS * 3;
    float mn[3] = { INFINITY, INFINITY, INFINITY };
    float mx[3] = { -INFINITY, -INFINITY, -INFINITY };
    for (int i = threadIdx.x; i < NPTS; i += 256) {
        float v0 = pb[3 * i + 0], v1 = pb[3 * i + 1], v2 = pb[3 * i + 2];
        mn[0] = fminf(mn[0], v0); mx[0] = fmaxf(mx[0], v0);
        mn[1] = fminf(mn[1], v1); mx[1] = fmaxf(mx[1], v1);
        mn[2] = fminf(mn[2], v2); mx[2] = fmaxf(mx[2], v2);
    }
#pragma unroll
    for (int off = 32; off > 0; off >>= 1) {
#pragma unroll
        for (int a = 0; a < 3; ++a) {
            mn[a] = fminf(mn[a], __shfl_down(mn[a], off));
            mx[a] = fmaxf(mx[a], __shfl_down(mx[a], off));
        }
    }
    int w = threadIdx.x >> 6, lane = threadIdx.x & 63;
    if (lane == 0) {
#pragma unroll
        for (int a = 0; a < 3; ++a) { smn[a][w] = mn[a]; smx[a][w] = mx[a]; }
    }
    __syncthreads();
    if (threadIdx.x == 0) {
#pragma unroll
        for (int a = 0; a < 3; ++a) {
            float m = smn[a][0], M = smx[a][0];
#pragma unroll
            for (int w2 = 1; w2 < 4; ++w2) { m = fminf(m, smn[a][w2]); M = fmaxf(M, smx[a][w2]); }
            bboxb[g * 6 + a] = m; bboxb[g * 6 + 3 + a] = M;
        }
    }
}

// ---------------------------------------------------------------- bin count
__global__ __launch_bounds__(256) void bin_count(const float* __restrict__ pos,
                                                 const float* __restrict__ bboxb,
                                                 unsigned* __restrict__ hist)
{
    const int i = blockIdx.x * 256 + threadIdx.x;       // 0..65535
    const int g = i >> 12;
    const float* pp = pos + (size_t)i * 3;
    float x = pp[0], y = pp[1], z = pp[2];
    float mnx = bboxb[g*6+0], mny = bboxb[g*6+1], mnz = bboxb[g*6+2];
    float iwx = (float)GC / fmaxf(bboxb[g*6+3] - mnx, 1e-9f);
    float iwy = (float)GC / fmaxf(bboxb[g*6+4] - mny, 1e-9f);
    float iwz = (float)GC / fmaxf(bboxb[g*6+5] - mnz, 1e-9f);
    int cell = (cell_coord(z, mnz, iwz) * GC + cell_coord(y, mny, iwy)) * GC + cell_coord(x, mnx, iwx);
    atomicAdd(&hist[g * NCELL + cell], 1u);
}

// ---------------------------------------------------------------- bin scan (per graph)
__global__ __launch_bounds__(256) void bin_scan(const unsigned* __restrict__ hist,
                                                unsigned* __restrict__ startb,
                                                unsigned* __restrict__ cursor)
{
    __shared__ unsigned psum[256];
    const int g = blockIdx.x;
    const int t = threadIdx.x;
    unsigned loc[16];
    unsigned s = 0;
    const unsigned* hb = hist + g * NCELL + t * 16;
#pragma unroll
    for (int k = 0; k < 16; ++k) { loc[k] = s; s += hb[k]; }
    psum[t] = s;
    __syncthreads();
    for (int off = 1; off < 256; off <<= 1) {
        unsigned add = (t >= off) ? psum[t - off] : 0u;
        __syncthreads();
        psum[t] += add;
        __syncthreads();
    }
    unsigned ebase = psum[t] - s;                       // exclusive prefix
    unsigned* sb = startb + g * NCELL + t * 16;
    unsigned* cb = cursor + g * NCELL + t * 16;
#pragma unroll
    for (int k = 0; k < 16; ++k) { unsigned v = ebase + loc[k]; sb[k] = v; cb[k] = v; }
}

// ---------------------------------------------------------------- bin scatter
__global__ __launch_bounds__(256) void bin_scatter(const float* __restrict__ pos,
                                                   const float* __restrict__ bboxb,
                                                   unsigned* __restrict__ cursor,
                                                   float4* __restrict__ sPt,
                                                   unsigned* __restrict__ sIdx)
{
    const int i = blockIdx.x * 256 + threadIdx.x;
    const int g = i >> 12;
    const float* pp = pos + (size_t)i * 3;
    float x = pp[0], y = pp[1], z = pp[2];
    float mnx = bboxb[g*6+0], mny = bboxb[g*6+1], mnz = bboxb[g*6+2];
    float iwx = (float)GC / fmaxf(bboxb[g*6+3] - mnx, 1e-9f);
    float iwy = (float)GC / fmaxf(bboxb[g*6+4] - mny, 1e-9f);
    float iwz = (float)GC / fmaxf(bboxb[g*6+5] - mnz, 1e-9f);
    int cell = (cell_coord(z, mnz, iwz) * GC + cell_coord(y, mny, iwy)) * GC + cell_coord(x, mnx, iwx);
    unsigned slot = atomicAdd(&cursor[g * NCELL + cell], 1u);
    float sq = __fadd_rn(__fadd_rn(__fmul_rn(x, x), __fmul_rn(y, y)), __fmul_rn(z, z));
    sPt[(size_t)g * NPTS + slot] = make_float4(x, y, z, sq);
    sIdx[(size_t)g * NPTS + slot] = (unsigned)(i & (NPTS - 1));   // local original index
}

// ---------------------------------------------------------------- grid KNN
// block -> (graph, qchunk, split). Thread = one query (scatter-rank order,
// spatially coherent waves) x one mod-4 stripe of each cell's contents.
// Pass 1: expanding Chebyshev rings, med3 top-10 VALUES; stop when
// bd[9] < (R*wmin)^2*0.999 (conservative; hard cap = full grid).
// Pass 2: re-walk rings 0..Rstop collecting (d2, idx) with d2 <= thr.
// Exactness: merge is lexicographic (d2, idx) -> visit order irrelevant.
__global__ __launch_bounds__(256) void knn_grid(const float4* __restrict__ sPt,
                                                const unsigned* __restrict__ sIdx,
                                                const unsigned* __restrict__ startb,
                                                const float* __restrict__ bboxb,
                                                uint2* __restrict__ pdi)
{
    __shared__ unsigned short sStart[NCELL + 1];        // 8194 B
    const int bid = blockIdx.x;
    const int s = bid & 3;
    const int chunk = (bid >> 2) & 15;
    const int g = bid >> 6;
    for (int c = threadIdx.x; c < NCELL; c += 256)
        sStart[c] = (unsigned short)startb[g * NCELL + c];
    if (threadIdx.x == 0) sStart[NCELL] = (unsigned short)NPTS;
    __syncthreads();

    const float mnx = bboxb[g*6+0], mny = bboxb[g*6+1], mnz = bboxb[g*6+2];
    const float rx = fmaxf(bboxb[g*6+3] - mnx, 1e-9f);
    const float ry = fmaxf(bboxb[g*6+4] - mny, 1e-9f);
    const float rz = fmaxf(bboxb[g*6+5] - mnz, 1e-9f);
    const float iwx = (float)GC / rx, iwy = (float)GC / ry, iwz = (float)GC / rz;
    const float wmin = fminf(rx, fminf(ry, rz)) * (1.f / (float)GC);

    const int r = chunk * 256 + (int)threadIdx.x;       // scatter rank
    const float4* pts = sPt + (size_t)g * NPTS;
    const float4 q = pts[r];
    const int qcx = cell_coord(q.x, mnx, iwx);
    const int qcy = cell_coord(q.y, mny, iwy);
    const int qcz = cell_coord(q.z, mnz, iwz);

    float bd[KNN];
#pragma unroll
    for (int m = 0; m < KNN; ++m) bd[m] = INFINITY;

    int Rstop = GC - 1;
    for (int R = 0; R < GC; ++R) {
        for (int dz = -R; dz <= R; ++dz) {
            int az = dz < 0 ? -dz : dz;
            for (int dy = -R; dy <= R; ++dy) {
                int ay = dy < 0 ? -dy : dy;
                int am = az > ay ? az : ay;
                int step = (am == R) ? 1 : (2 * R);     // shell-only enumeration
                for (int dx = -R; dx <= R; dx += step) {
                    int cx = qcx + dx, cy = qcy + dy, cz = qcz + dz;
                    bool ok = ((unsigned)cx < (unsigned)GC) && ((unsigned)cy < (unsigned)GC)
                           && ((unsigned)cz < (unsigned)GC);
                    int cl = ok ? ((cz * GC + cy) * GC + cx) : 0;
                    int j0 = ok ? ((int)sStart[cl] + s) : 1;
                    int j1 = ok ? (int)sStart[cl + 1] : 0;
                    for (int j = j0; j < j1; j += NSPLIT) {
                        float4 p = pts[j];
                        float dot = __fadd_rn(__fadd_rn(__fmul_rn(q.x, p.x), __fmul_rn(q.y, p.y)),
                                              __fmul_rn(q.z, p.z));
                        float d2 = __fsub_rn(__fadd_rn(q.w, p.w), __fmul_rn(2.f, dot));
#pragma unroll
                        for (int m = KNN - 1; m > 0; --m) bd[m] = med3_f(d2, bd[m - 1], bd[m]);
                        bd[0] = fminf(d2, bd[0]);
                    }
                }
            }
        }
        float rb = (float)R * wmin;
        if (__all(bd[KNN - 1] < rb * rb * 0.999f)) { Rstop = R; break; }
    }
    const float thr = bd[KNN - 1];

    const int qi = (int)sIdx[(size_t)g * NPTS + r];
    uint2* o = pdi + ((size_t)(g * NPTS + qi) * NSPLIT + s) * SLOTS;
    int cnt = 0;
    for (int R = 0; R <= Rstop; ++R) {
        for (int dz = -R; dz <= R; ++dz) {
            int az = dz < 0 ? -dz : dz;
            for (int dy = -R; dy <= R; ++dy) {
                int ay = dy < 0 ? -dy : dy;
                int am = az > ay ? az : ay;
                int step = (am == R) ? 1 : (2 * R);
                for (int dx = -R; dx <= R; dx += step) {
                    int cx = qcx + dx, cy = qcy + dy, cz = qcz + dz;
                    bool ok = ((unsigned)cx < (unsigned)GC) && ((unsigned)cy < (unsigned)GC)
                           && ((unsigned)cz < (unsigned)GC);
                    int cl = ok ? ((cz * GC + cy) * GC + cx) : 0;
                    int j0 = ok ? ((int)sStart[cl] + s) : 1;
                    int j1 = ok ? (int)sStart[cl + 1] : 0;
                    for (int j = j0; j < j1; j += NSPLIT) {
                        float4 p = pts[j];
                        float dot = __fadd_rn(__fadd_rn(__fmul_rn(q.x, p.x), __fmul_rn(q.y, p.y)),
                                              __fmul_rn(q.z, p.z));
                        float d2 = __fsub_rn(__fadd_rn(q.w, p.w), __fmul_rn(2.f, dot));
                        if (d2 <= thr && cnt < SLOTS) {
                            o[cnt] = make_uint2(__float_as_uint(d2), sIdx[(size_t)g * NPTS + j]);
                            ++cnt;
                        }
                    }
                }
            }
        }
    }
}

// ---------------------------------------------------------------- KNN merge (lexicographic)
// Exact 10 smallest by (d2, original index) == lax.top_k stable tie-break,
// independent of candidate arrival order. NaN entries fail all compares.
__global__ __launch_bounds__(256) void knn_merge(const uint2* __restrict__ pdi,
                                                 int* __restrict__ nbr)
{
    const int q = blockIdx.x * 256 + threadIdx.x;
    const uint2* in = pdi + (size_t)q * (NSPLIT * SLOTS);
    float bd[KNN];
    int   bi[KNN];
#pragma unroll
    for (int m = 0; m < KNN; ++m) { bd[m] = 3.4e38f; bi[m] = 0x7fffffff; }
#pragma unroll
    for (int u = 0; u < NSPLIT * SLOTS; ++u) {
        uint2 v = in[u];
        float d2 = __uint_as_float(v.x);
        int   ix = (int)v.y;
        if ((d2 < bd[KNN - 1]) || (d2 == bd[KNN - 1] && ix < bi[KNN - 1])) {
            bool c[KNN];
#pragma unroll
            for (int m = 0; m < KNN; ++m) c[m] = (d2 < bd[m]) || (d2 == bd[m] && ix < bi[m]);
#pragma unroll
            for (int m = KNN - 1; m > 0; --m) {
                bd[m] = c[m] ? (c[m - 1] ? bd[m - 1] : d2) : bd[m];
                bi[m] = c[m] ? (c[m - 1] ? bi[m - 1] : ix) : bi[m];
            }
            bd[0] = c[0] ? d2 : bd[0];
            bi[0] = c[0] ? ix : bi[0];
        }
    }
    const int b = q >> 12;
    int* o = nbr + (size_t)q * KNN;
#pragma unroll
    for (int m = 0; m < KNN; ++m) o[m] = (b << 12) + bi[m];
}

// ---------------------------------------------------------------- W pre-permute (unchanged)
__global__ __launch_bounds__(256) void wprep(const float* __restrict__ Wc,
                                             const float* __restrict__ W1,
                                             unsigned* __restrict__ whi,
                                             unsigned* __restrict__ wlo)
{
    const int m = blockIdx.x;
    const float* W = (m < 4) ? (Wc + m * 16384) : W1;
    unsigned* oh = whi + m * 8192;
    unsigned* ol = wlo + m * 8192;
    for (int u = threadIdx.x; u < 8192; u += 256) {
        int kk = u >> 11, ct = (u >> 8) & 7, l = (u >> 2) & 63, d = u & 3;
        int k0 = kk * 32 + ((l >> 4) << 3) + 2 * d;
        int c  = ct * 16 + (l & 15);
        float f0 = W[k0 * 128 + c], f1 = W[(k0 + 1) * 128 + c];
        unsigned h0 = bf16_rne(f0), h1 = bf16_rne(f1);
        float r0 = f0 - bf2f(h0), r1 = f1 - bf2f(h1);
        oh[u] = h0 | (h1 << 16);
        ol[u] = bf16_rne(r0) | (bf16_rne(r1) << 16);
    }
}

// ---------------------------------------------------------------- x0 = relu(pos@W0+b0)
__global__ __launch_bounds__(256) void x0_kernel(const float* __restrict__ pos,
                                                 const float* __restrict__ W0,
                                                 const float* __restrict__ b0,
                                                 float* __restrict__ x0)
{
    int gid = blockIdx.x * 256 + threadIdx.x;
    int node = gid >> 5, qd = gid & 31;
    float px = pos[node * 3 + 0], py = pos[node * 3 + 1], pz = pos[node * 3 + 2];
    const float4 w0 = ((const float4*)W0)[qd];
    const float4 w1 = ((const float4*)W0)[32 + qd];
    const float4 w2 = ((const float4*)W0)[64 + qd];
    const float4 bb = ((const float4*)b0)[qd];
    float4 r;
    r.x = relu_f(fmaf(pz, w2.x, fmaf(py, w1.x, fmaf(px, w0.x, bb.x))));
    r.y = relu_f(fmaf(pz, w2.y, fmaf(py, w1.y, fmaf(px, w0.y, bb.y))));
    r.z = relu_f(fmaf(pz, w2.z, fmaf(py, w1.z, fmaf(px, w0.z, bb.z))));
    r.w = relu_f(fmaf(pz, w2.w, fmaf(py, w1.w, fmaf(px, w0.w, bb.w))));
    ((float4*)x0)[gid] = r;
}

// ---------------------------------------------------------------- MFMA GEMM step (unchanged)
__device__ __forceinline__ void gemm_kk(const float* shrow, const unsigned* sB,
                                        int l, f32x4* acc)
{
    float f[8];
#pragma unroll
    for (int j = 0; j < 8; ++j) f[j] = shrow[j];
    unsigned ah[4], al[4];
#pragma unroll
    for (int d = 0; d < 4; ++d) {
        unsigned h0 = bf16_rne(f[2 * d]), h1 = bf16_rne(f[2 * d + 1]);
        ah[d] = h0 | (h1 << 16);
        float r0 = f[2 * d] - bf2f(h0), r1 = f[2 * d + 1] - bf2f(h1);
        al[d] = bf16_rne(r0) | (bf16_rne(r1) << 16);
    }
    i32x4 ahv = { (int)ah[0], (int)ah[1], (int)ah[2], (int)ah[3] };
    i32x4 alv = { (int)al[0], (int)al[1], (int)al[2], (int)al[3] };
    s16x8 Ah = __builtin_bit_cast(s16x8, ahv);
    s16x8 Al = __builtin_bit_cast(s16x8, alv);
#pragma unroll
    for (int ct = 0; ct < 8; ++ct) {
        i32x4 bh = *(const i32x4*)&sB[(ct * 64 + l) * 4];
        i32x4 bl = *(const i32x4*)&sB[2048 + (ct * 64 + l) * 4];
        s16x8 Bh = __builtin_bit_cast(s16x8, bh);
        s16x8 Bl = __builtin_bit_cast(s16x8, bl);
        acc[ct] = __builtin_amdgcn_mfma_f32_16x16x32_bf16(Ah, Bh, acc[ct], 0, 0, 0);
        acc[ct] = __builtin_amdgcn_mfma_f32_16x16x32_bf16(Al, Bh, acc[ct], 0, 0, 0);
        acc[ct] = __builtin_amdgcn_mfma_f32_16x16x32_bf16(Ah, Bl, acc[ct], 0, 0, 0);
    }
}

// ---------------------------------------------------------------- fused GCN2 layer (unchanged)
__global__ __launch_bounds__(256) void gcn_layer(const float* __restrict__ xin,
                                                 float* __restrict__ xout,
                                                 const float* __restrict__ pos,
                                                 const float* __restrict__ W0,
                                                 const float* __restrict__ b0,
                                                 const unsigned* __restrict__ whi,
                                                 const unsigned* __restrict__ wlo,
                                                 const int* __restrict__ nbr,
                                                 float omb, float beta)
{
    __shared__ float sh[64][129];
    __shared__ __align__(16) unsigned sB[4096];
    __shared__ float sW0[512];
    const int t = threadIdx.x;
    const int bid = blockIdx.x;
    const int swz = (bid & 7) * 128 + (bid >> 3);
    const int node0 = swz * 64;

    if (t < 128) {
        sW0[t] = W0[t]; sW0[128 + t] = W0[128 + t];
        sW0[256 + t] = W0[256 + t]; sW0[384 + t] = b0[t];
    }
    __syncthreads();

    const float4* xin4 = (const float4*)xin;
    for (int u = t; u < 64 * 32; u += 256) {
        int n = u >> 5, qd = u & 31;
        int node = node0 + n;
        float ax = 0.f, ay = 0.f, az = 0.f, aw = 0.f;
        const int* nb = nbr + node * KNN;
#pragma unroll
        for (int k = 0; k < KNN; ++k) {
            float4 v = xin4[nb[k] * 32 + qd];
            ax += v.x; ay += v.y; az += v.z; aw += v.w;
        }
        float px = pos[node * 3 + 0], py = pos[node * 3 + 1], pz = pos[node * 3 + 2];
        int c = qd * 4;
        sh[n][c + 0] = fmaf(0.9f, ax, 0.1f * relu_f(fmaf(pz, sW0[256 + c + 0], fmaf(py, sW0[128 + c + 0], fmaf(px, sW0[c + 0], sW0[384 + c + 0])))));
        sh[n][c + 1] = fmaf(0.9f, ay, 0.1f * relu_f(fmaf(pz, sW0[256 + c + 1], fmaf(py, sW0[128 + c + 1], fmaf(px, sW0[c + 1], sW0[384 + c + 1])))));
        sh[n][c + 2] = fmaf(0.9f, az, 0.1f * relu_f(fmaf(pz, sW0[256 + c + 2], fmaf(py, sW0[128 + c + 2], fmaf(px, sW0[c + 2], sW0[384 + c + 2])))));
        sh[n][c + 3] = fmaf(0.9f, aw, 0.1f * relu_f(fmaf(pz, sW0[256 + c + 3], fmaf(py, sW0[128 + c + 3], fmaf(px, sW0[c + 3], sW0[384 + c + 3])))));
    }

    const int w = t >> 6, l = t & 63, lr = l & 15, lg = l >> 4;
    f32x4 acc[8];
    const f32x4 z4 = { 0.f, 0.f, 0.f, 0.f };
#pragma unroll
    for (int ct = 0; ct < 8; ++ct) acc[ct] = z4;

    for (int kk = 0; kk < 4; ++kk) {
        __syncthreads();
        const uint4* srch = (const uint4*)(whi + kk * 2048);
        const uint4* srcl = (const uint4*)(wlo + kk * 2048);
        uint4* dst = (uint4*)sB;
        dst[t] = srch[t];           dst[256 + t] = srch[256 + t];
        dst[512 + t] = srcl[t];     dst[768 + t] = srcl[256 + t];
        __syncthreads();
        gemm_kk(&sh[w * 16 + lr][kk * 32 + lg * 8], sB, l, acc);
    }

#pragma unroll
    for (int ct = 0; ct < 8; ++ct) {
        int col = ct * 16 + lr;
#pragma unroll
        for (int r = 0; r < 4; ++r) {
            int rw = w * 16 + lg * 4 + r;
            float h = sh[rw][col];
            xout[(size_t)(node0 + rw) * HDIM + col] = relu_f(fmaf(omb, h, beta * acc[ct][r]));
        }
    }
}

// ---------------------------------------------------------------- w1 + max-pool (unchanged)
__global__ __launch_bounds__(256) void w1pool_kernel(const float* __restrict__ xin,
                                                     const unsigned* __restrict__ whi,
                                                     const unsigned* __restrict__ wlo,
                                                     const float* __restrict__ b1,
                                                     unsigned int* __restrict__ pool)
{
    __shared__ float sh[64][129];
    __shared__ __align__(16) unsigned sB[4096];
    __shared__ float smax[16][128];
    const int t = threadIdx.x;
    const int bid = blockIdx.x;
    const int swz = (bid & 7) * 128 + (bid >> 3);
    const int node0 = swz * 64;

    const float4* xin4 = (const float4*)xin;
    for (int u = t; u < 64 * 32; u += 256) {
        int n = u >> 5, qd = u & 31;
        float4 v = xin4[(node0 + n) * 32 + qd];
        int c = qd * 4;
        sh[n][c + 0] = v.x; sh[n][c + 1] = v.y; sh[n][c + 2] = v.z; sh[n][c + 3] = v.w;
    }

    const int w = t >> 6, l = t & 63, lr = l & 15, lg = l >> 4;
    f32x4 acc[8];
    const f32x4 z4 = { 0.f, 0.f, 0.f, 0.f };
#pragma unroll
    for (int ct = 0; ct < 8; ++ct) acc[ct] = z4;

    for (int kk = 0; kk < 4; ++kk) {
        __syncthreads();
        const uint4* srch = (const uint4*)(whi + kk * 2048);
        const uint4* srcl = (const uint4*)(wlo + kk * 2048);
        uint4* dst = (uint4*)sB;
        dst[t] = srch[t];           dst[256 + t] = srch[256 + t];
        dst[512 + t] = srcl[t];     dst[768 + t] = srcl[256 + t];
        __syncthreads();
        gemm_kk(&sh[w * 16 + lr][kk * 32 + lg * 8], sB, l, acc);
    }

#pragma unroll
    for (int ct = 0; ct < 8; ++ct) {
        int col = ct * 16 + lr;
        float m = fmaxf(fmaxf(acc[ct][0], acc[ct][1]), fmaxf(acc[ct][2], acc[ct][3]));
        smax[w * 4 + lg][col] = m + b1[col];
    }
    __syncthreads();
    if (t < 128) {
        float m = smax[0][t];
#pragma unroll
        for (int r = 1; r < 16; ++r) m = fmaxf(m, smax[r][t]);
        unsigned int u = __float_as_uint(m);
        unsigned int key = (u & 0x80000000u) ? ~u : (u | 0x80000000u);
        atomicMax(&pool[(node0 >> 12) * HDIM + t], key);
    }
}

// ---------------------------------------------------------------- MLP head (unchanged)
__global__ __launch_bounds__(256) void head_kernel(const unsigned int* __restrict__ pool,
                                                   const float* __restrict__ Wm1, const float* __restrict__ bm1,
                                                   const float* __restrict__ g1,  const float* __restrict__ be1,
                                                   const float* __restrict__ Wm2, const float* __restrict__ bm2,
                                                   const float* __restrict__ g2,  const float* __restrict__ be2,
                                                   const float* __restrict__ Wout,const float* __restrict__ bout,
                                                   float* __restrict__ out)
{
    __shared__ float sA[16][128];
    __shared__ float sB2[16][128];
    __shared__ float sL[16][10];
    const int t = threadIdx.x;
    for (int u = t; u < 2048; u += 256) {
        unsigned int k = pool[u];
        unsigned int orig = (k & 0x80000000u) ? (k ^ 0x80000000u) : ~k;
        sA[u >> 7][u & 127] = __uint_as_float(orig);
    }
    __syncthreads();

    if (t < 128) {
        float y[16];
#pragma unroll
        for (int b = 0; b < 16; ++b) y[b] = bm1[t];
        for (int i = 0; i < 128; ++i) {
            float w = Wm1[i * 128 + t];
#pragma unroll
            for (int b = 0; b < 16; ++b) y[b] = fmaf(sA[b][i], w, y[b]);
        }
        float mu = 0.f;
#pragma unroll
        for (int b = 0; b < 16; ++b) mu += y[b];
        mu *= (1.f / 16.f);
        float var = 0.f;
#pragma unroll
        for (int b = 0; b < 16; ++b) { float d = y[b] - mu; var = fmaf(d, d, var); }
        var *= (1.f / 16.f);
        float sc = g1[t] / sqrtf(var + 1e-5f);
        float sb = be1[t];
#pragma unroll
        for (int b = 0; b < 16; ++b) sB2[b][t] = relu_f((y[b] - mu) * sc + sb);
    }
    __syncthreads();

    if (t < 128) {
        float y[16];
#pragma unroll
        for (int b = 0; b < 16; ++b) y[b] = bm2[t];
        for (int i = 0; i < 128; ++i) {
            float w = Wm2[i * 128 + t];
#pragma unroll
            for (int b = 0; b < 16; ++b) y[b] = fmaf(sB2[b][i], w, y[b]);
        }
        float mu = 0.f;
#pragma unroll
        for (int b = 0; b < 16; ++b) mu += y[b];
        mu *= (1.f / 16.f);
        float var = 0.f;
#pragma unroll
        for (int b = 0; b < 16; ++b) { float d = y[b] - mu; var = fmaf(d, d, var); }
        var *= (1.f / 16.f);
        float sc = g2[t] / sqrtf(var + 1e-5f);
        float sb = be2[t];
#pragma unroll
        for (int b = 0; b < 16; ++b) sA[b][t] = relu_f((y[b] - mu) * sc + sb);
    }
    __syncthreads();

    if (t < 160) {
        int b = t / 10, o = t % 10;
        float a = bout[o];
        for (int i = 0; i < 128; ++i) a = fmaf(sA[b][i], Wout[i * 10 + o], a);
        sL[b][o] = a;
    }
    __syncthreads();

    if (t < 16) {
        float m = sL[t][0];
#pragma unroll
        for (int o = 1; o < 10; ++o) m = fmaxf(m, sL[t][o]);
        float s = 0.f;
#pragma unroll
        for (int o = 0; o < 10; ++o) s += expf(sL[t][o] - m);
        float ls = logf(s);
#pragma unroll
        for (int o = 0; o < 10; ++o) out[t * 10 + o] = sL[t][o] - m - ls;
    }
}

// ----------------------------------------------------------------
extern "C" void kernel_launch(void* const* d_in, const int* in_sizes, int n_in,
                              void* d_out, int out_size, void* d_ws, size_t ws_size,
                              hipStream_t stream)
{
    const float* pos = (const float*)d_in[0];
    const float* W0  = (const float*)d_in[1];
    const float* b0  = (const float*)d_in[2];
    const float* Wc  = (const float*)d_in[3];
    const float* W1  = (const float*)d_in[4];
    const float* b1  = (const float*)d_in[5];
    const float* Wm1 = (const float*)d_in[6];
    const float* bm1 = (const float*)d_in[7];
    const float* g1  = (const float*)d_in[8];
    const float* be1 = (const float*)d_in[9];
    const float* Wm2 = (const float*)d_in[10];
    const float* bm2 = (const float*)d_in[11];
    const float* g2  = (const float*)d_in[12];
    const float* be2 = (const float*)d_in[13];
    const float* Wout= (const float*)d_in[14];
    const float* bout= (const float*)d_in[15];
    float* out = (float*)d_out;

    char* ws = (char*)d_ws;
    float*        xA   = (float*)ws;                       // 33,554,432 B
    float*        xB   = (float*)(ws + 33554432);          // 33,554,432 B
    int*          nbr  = (int*)(ws + 67108864);            //  2,621,440 B
    unsigned int* pool = (unsigned int*)(ws + 69730304);   //      8,192 B
    unsigned*     whi  = (unsigned*)(ws + 69738496);       //    163,840 B
    unsigned*     wlo  = (unsigned*)(ws + 69902336);       //    163,840 B
    // KNN scratch: aliases xA (pdi) and xB (grid data) -- all dead before x0/gcn.
    uint2*    pdi    = (uint2*)ws;                         // 25,165,824 B @0
    float4*   sPt    = (float4*)(ws + 33554432);           //  1,048,576 B
    unsigned* sIdx   = (unsigned*)(ws + 34603008);         //    262,144 B
    unsigned* startb = (unsigned*)(ws + 34865152);         //    262,144 B
    unsigned* cursor = (unsigned*)(ws + 35127296);         //    262,144 B
    unsigned* hist   = (unsigned*)(ws + 35389440);         //    262,144 B
    float*    bboxb  = (float*)(ws + 35651584);            //        384 B

    bbox_kernel<<<16, 256, 0, stream>>>(pos, bboxb);
    hipMemsetAsync(hist, 0, 16 * NCELL * sizeof(unsigned), stream);
    bin_count<<<256, 256, 0, stream>>>(pos, bboxb, hist);
    bin_scan<<<16, 256, 0, stream>>>(hist, startb, cursor);
    bin_scatter<<<256, 256, 0, stream>>>(pos, bboxb, cursor, sPt, sIdx);
    hipMemsetAsync(pdi, 0xFF, (size_t)16 * NPTS * NSPLIT * SLOTS * 8, stream);
    wprep<<<5, 256, 0, stream>>>(Wc, W1, whi, wlo);
    knn_grid<<<1024, 256, 0, stream>>>(sPt, sIdx, startb, bboxb, pdi);
    knn_merge<<<256, 256, 0, stream>>>(pdi, nbr);
    x0_kernel<<<8192, 256, 0, stream>>>(pos, W0, b0, xA);

    const float betas[4] = { 0.40546510810816438f, 0.22314355131420976f,
                             0.15415067982725836f, 0.11778303565638346f };
    gcn_layer<<<1024, 256, 0, stream>>>(xA, xB, pos, W0, b0, whi + 0 * 8192, wlo + 0 * 8192, nbr, 1.f - betas[0], betas[0]);
    gcn_layer<<<1024, 256, 0, stream>>>(xB, xA, pos, W0, b0, whi + 1 * 8192, wlo + 1 * 8192, nbr, 1.f - betas[1], betas[1]);
    gcn_layer<<<1024, 256, 0, stream>>>(xA, xB, pos, W0, b0, whi + 2 * 8192, wlo + 2 * 8192, nbr, 1.f - betas[2], betas[2]);
    gcn_layer<<<1024, 256, 0, stream>>>(xB, xA, pos, W0, b0, whi + 3 * 8192, wlo + 3 * 8192, nbr, 1.f - betas[3], betas[3]);

    hipMemsetAsync(pool, 0, 16 * HDIM * sizeof(unsigned int), stream);
    w1pool_kernel<<<1024, 256, 0, stream>>>(xA, whi + 4 * 8192, wlo + 4 * 8192, b1, pool);
    head_kernel<<<1, 256, 0, stream>>>(pool, Wm1, bm1, g1, be1, Wm2, bm2, g2, be2, Wout, bout, out);
}

// Round 10
// 2298.548 us; speedup vs baseline: 1.5989x; 1.5989x over previous
//
#include <hip/hip_runtime.h>
#include <math.h>

#define NPTS 4096
#define HDIM 128
#define KNN 10
#define NSPLIT 4
#define SLOTS 12
#define GC 8
#define NCELL 512    // GC^3

typedef __attribute__((ext_vector_type(4))) float f32x4;
typedef __attribute__((ext_vector_type(4))) int   i32x4;
typedef __attribute__((ext_vector_type(8))) short s16x8;

__device__ __forceinline__ float relu_f(float x) { return x > 0.f ? x : 0.f; }
__device__ __forceinline__ float med3_f(float a, float b, float c) {
    return __builtin_amdgcn_fmed3f(a, b, c);
}
__device__ __forceinline__ unsigned bf16_rne(float f) {
    unsigned u = __float_as_uint(f);
    return (u + 0x7fffu + ((u >> 16) & 1u)) >> 16;
}
__device__ __forceinline__ float bf2f(unsigned h) { return __uint_as_float(h << 16); }

__device__ __forceinline__ int cell_coord(float v, float mn, float iw) {
    int c = (int)((v - mn) * iw);
    return min(GC - 1, max(0, c));
}

// ---------------------------------------------------------------- bbox per graph
__global__ __launch_bounds__(256) void bbox_kernel(const float* __restrict__ pos,
                                                   float* __restrict__ bboxb)
{
    __shared__ float smn[3][4], smx[3][4];
    const int g = blockIdx.x;
    const float* pb = pos + (size_t)g * NPTS * 3;
    float mn[3] = { INFINITY, INFINITY, INFINITY };
    float mx[3] = { -INFINITY, -INFINITY, -INFINITY };
    for (int i = threadIdx.x; i < NPTS; i += 256) {
        float v0 = pb[3 * i + 0], v1 = pb[3 * i + 1], v2 = pb[3 * i + 2];
        mn[0] = fminf(mn[0], v0); mx[0] = fmaxf(mx[0], v0);
        mn[1] = fminf(mn[1], v1); mx[1] = fmaxf(mx[1], v1);
        mn[2] = fminf(mn[2], v2); mx[2] = fmaxf(mx[2], v2);
    }
#pragma unroll
    for (int off = 32; off > 0; off >>= 1) {
#pragma unroll
        for (int a = 0; a < 3; ++a) {
            mn[a] = fminf(mn[a], __shfl_down(mn[a], off));
            mx[a] = fmaxf(mx[a], __shfl_down(mx[a], off));
        }
    }
    int w = threadIdx.x >> 6, lane = threadIdx.x & 63;
    if (lane == 0) {
#pragma unroll
        for (int a = 0; a < 3; ++a) { smn[a][w] = mn[a]; smx[a][w] = mx[a]; }
    }
    __syncthreads();
    if (threadIdx.x == 0) {
#pragma unroll
        for (int a = 0; a < 3; ++a) {
            float m = smn[a][0], M = smx[a][0];
#pragma unroll
            for (int w2 = 1; w2 < 4; ++w2) { m = fminf(m, smn[a][w2]); M = fmaxf(M, smx[a][w2]); }
            bboxb[g * 6 + a] = m; bboxb[g * 6 + 3 + a] = M;
        }
    }
}

// ---------------------------------------------------------------- bin count
__global__ __launch_bounds__(256) void bin_count(const float* __restrict__ pos,
                                                 const float* __restrict__ bboxb,
                                                 unsigned* __restrict__ hist)
{
    const int i = blockIdx.x * 256 + threadIdx.x;       // 0..65535
    const int g = i >> 12;
    const float* pp = pos + (size_t)i * 3;
    float x = pp[0], y = pp[1], z = pp[2];
    float mnx = bboxb[g*6+0], mny = bboxb[g*6+1], mnz = bboxb[g*6+2];
    float iwx = (float)GC / fmaxf(bboxb[g*6+3] - mnx, 1e-9f);
    float iwy = (float)GC / fmaxf(bboxb[g*6+4] - mny, 1e-9f);
    float iwz = (float)GC / fmaxf(bboxb[g*6+5] - mnz, 1e-9f);
    int cell = (cell_coord(z, mnz, iwz) * GC + cell_coord(y, mny, iwy)) * GC + cell_coord(x, mnx, iwx);
    atomicAdd(&hist[g * NCELL + cell], 1u);
}

// ---------------------------------------------------------------- bin scan (per graph, NCELL=512 -> 2 cells/thread)
__global__ __launch_bounds__(256) void bin_scan(const unsigned* __restrict__ hist,
                                                unsigned* __restrict__ startb,
                                                unsigned* __restrict__ cursor)
{
    __shared__ unsigned psum[256];
    const int g = blockIdx.x;
    const int t = threadIdx.x;
    const unsigned* hb = hist + g * NCELL + t * 2;
    unsigned h0 = hb[0], h1 = hb[1];
    unsigned s = h0 + h1;
    psum[t] = s;
    __syncthreads();
    for (int off = 1; off < 256; off <<= 1) {
        unsigned add = (t >= off) ? psum[t - off] : 0u;
        __syncthreads();
        psum[t] += add;
        __syncthreads();
    }
    unsigned ebase = psum[t] - s;                       // exclusive prefix
    unsigned* sb = startb + g * NCELL + t * 2;
    unsigned* cb = cursor + g * NCELL + t * 2;
    sb[0] = ebase;      cb[0] = ebase;
    sb[1] = ebase + h0; cb[1] = ebase + h0;
}

// ---------------------------------------------------------------- bin scatter
__global__ __launch_bounds__(256) void bin_scatter(const float* __restrict__ pos,
                                                   const float* __restrict__ bboxb,
                                                   unsigned* __restrict__ cursor,
                                                   float4* __restrict__ sPt,
                                                   unsigned* __restrict__ sIdx)
{
    const int i = blockIdx.x * 256 + threadIdx.x;
    const int g = i >> 12;
    const float* pp = pos + (size_t)i * 3;
    float x = pp[0], y = pp[1], z = pp[2];
    float mnx = bboxb[g*6+0], mny = bboxb[g*6+1], mnz = bboxb[g*6+2];
    float iwx = (float)GC / fmaxf(bboxb[g*6+3] - mnx, 1e-9f);
    float iwy = (float)GC / fmaxf(bboxb[g*6+4] - mny, 1e-9f);
    float iwz = (float)GC / fmaxf(bboxb[g*6+5] - mnz, 1e-9f);
    int cell = (cell_coord(z, mnz, iwz) * GC + cell_coord(y, mny, iwy)) * GC + cell_coord(x, mnx, iwx);
    unsigned slot = atomicAdd(&cursor[g * NCELL + cell], 1u);
    float sq = __fadd_rn(__fadd_rn(__fmul_rn(x, x), __fmul_rn(y, y)), __fmul_rn(z, z));
    sPt[(size_t)g * NPTS + slot] = make_float4(x, y, z, sq);
    sIdx[(size_t)g * NPTS + slot] = (unsigned)(i & (NPTS - 1));   // local original index
}

// ---------------------------------------------------------------- grid KNN (GC=8)
// block -> (graph, qchunk, split). Thread = one query (scatter-rank order,
// spatially coherent waves) x one mod-4 stripe of each cell's contents.
// Pass 1: expanding Chebyshev rings, med3 top-10 VALUES; stop when
// bd[9] < (R*wmin)^2*0.999 (conservative; hard cap = full grid).
// Pass 2: re-walk rings 0..Rstop collecting (d2, idx) with d2 <= thr.
// Exactness: merge is lexicographic (d2, idx) -> visit order irrelevant.
__global__ __launch_bounds__(256) void knn_grid(const float4* __restrict__ sPt,
                                                const unsigned* __restrict__ sIdx,
                                                const unsigned* __restrict__ startb,
                                                const float* __restrict__ bboxb,
                                                uint2* __restrict__ pdi)
{
    __shared__ unsigned short sStart[NCELL + 1];        // 1026 B
    const int bid = blockIdx.x;
    const int s = bid & 3;
    const int chunk = (bid >> 2) & 15;
    const int g = bid >> 6;
    for (int c = threadIdx.x; c < NCELL; c += 256)
        sStart[c] = (unsigned short)startb[g * NCELL + c];
    if (threadIdx.x == 0) sStart[NCELL] = (unsigned short)NPTS;
    __syncthreads();

    const float mnx = bboxb[g*6+0], mny = bboxb[g*6+1], mnz = bboxb[g*6+2];
    const float rx = fmaxf(bboxb[g*6+3] - mnx, 1e-9f);
    const float ry = fmaxf(bboxb[g*6+4] - mny, 1e-9f);
    const float rz = fmaxf(bboxb[g*6+5] - mnz, 1e-9f);
    const float iwx = (float)GC / rx, iwy = (float)GC / ry, iwz = (float)GC / rz;
    const float wmin = fminf(rx, fminf(ry, rz)) * (1.f / (float)GC);

    const int r = chunk * 256 + (int)threadIdx.x;       // scatter rank
    const float4* pts = sPt + (size_t)g * NPTS;
    const float4 q = pts[r];
    const int qcx = cell_coord(q.x, mnx, iwx);
    const int qcy = cell_coord(q.y, mny, iwy);
    const int qcz = cell_coord(q.z, mnz, iwz);

    float bd[KNN];
#pragma unroll
    for (int m = 0; m < KNN; ++m) bd[m] = INFINITY;

    int Rstop = GC - 1;
    for (int R = 0; R < GC; ++R) {
        for (int dz = -R; dz <= R; ++dz) {
            int az = dz < 0 ? -dz : dz;
            for (int dy = -R; dy <= R; ++dy) {
                int ay = dy < 0 ? -dy : dy;
                int am = az > ay ? az : ay;
                int step = (am == R) ? 1 : (2 * R);     // shell-only enumeration
                for (int dx = -R; dx <= R; dx += step) {
                    int cx = qcx + dx, cy = qcy + dy, cz = qcz + dz;
                    bool ok = ((unsigned)cx < (unsigned)GC) && ((unsigned)cy < (unsigned)GC)
                           && ((unsigned)cz < (unsigned)GC);
                    int cl = ok ? ((cz * GC + cy) * GC + cx) : 0;
                    int j0 = ok ? ((int)sStart[cl] + s) : 1;
                    int j1 = ok ? (int)sStart[cl + 1] : 0;
                    for (int j = j0; j < j1; j += NSPLIT) {
                        float4 p = pts[j];
                        float dot = __fadd_rn(__fadd_rn(__fmul_rn(q.x, p.x), __fmul_rn(q.y, p.y)),
                                              __fmul_rn(q.z, p.z));
                        float d2 = __fsub_rn(__fadd_rn(q.w, p.w), __fmul_rn(2.f, dot));
#pragma unroll
                        for (int m = KNN - 1; m > 0; --m) bd[m] = med3_f(d2, bd[m - 1], bd[m]);
                        bd[0] = fminf(d2, bd[0]);
                    }
                }
            }
        }
        float rb = (float)R * wmin;
        if (__all(bd[KNN - 1] < rb * rb * 0.999f)) { Rstop = R; break; }
    }
    const float thr = bd[KNN - 1];

    const int qi = (int)sIdx[(size_t)g * NPTS + r];
    uint2* o = pdi + ((size_t)(g * NPTS + qi) * NSPLIT + s) * SLOTS;
    int cnt = 0;
    for (int R = 0; R <= Rstop; ++R) {
        for (int dz = -R; dz <= R; ++dz) {
            int az = dz < 0 ? -dz : dz;
            for (int dy = -R; dy <= R; ++dy) {
                int ay = dy < 0 ? -dy : dy;
                int am = az > ay ? az : ay;
                int step = (am == R) ? 1 : (2 * R);
                for (int dx = -R; dx <= R; dx += step) {
                    int cx = qcx + dx, cy = qcy + dy, cz = qcz + dz;
                    bool ok = ((unsigned)cx < (unsigned)GC) && ((unsigned)cy < (unsigned)GC)
                           && ((unsigned)cz < (unsigned)GC);
                    int cl = ok ? ((cz * GC + cy) * GC + cx) : 0;
                    int j0 = ok ? ((int)sStart[cl] + s) : 1;
                    int j1 = ok ? (int)sStart[cl + 1] : 0;
                    for (int j = j0; j < j1; j += NSPLIT) {
                        float4 p = pts[j];
                        float dot = __fadd_rn(__fadd_rn(__fmul_rn(q.x, p.x), __fmul_rn(q.y, p.y)),
                                              __fmul_rn(q.z, p.z));
                        float d2 = __fsub_rn(__fadd_rn(q.w, p.w), __fmul_rn(2.f, dot));
                        if (d2 <= thr && cnt < SLOTS) {
                            o[cnt] = make_uint2(__float_as_uint(d2), sIdx[(size_t)g * NPTS + j]);
                            ++cnt;
                        }
                    }
                }
            }
        }
    }
}

// ---------------------------------------------------------------- KNN merge (lexicographic)
__global__ __launch_bounds__(256) void knn_merge(const uint2* __restrict__ pdi,
                                                 int* __restrict__ nbr)
{
    const int q = blockIdx.x * 256 + threadIdx.x;
    const uint2* in = pdi + (size_t)q * (NSPLIT * SLOTS);
    float bd[KNN];
    int   bi[KNN];
#pragma unroll
    for (int m = 0; m < KNN; ++m) { bd[m] = 3.4e38f; bi[m] = 0x7fffffff; }
#pragma unroll
    for (int u = 0; u < NSPLIT * SLOTS; ++u) {
        uint2 v = in[u];
        float d2 = __uint_as_float(v.x);               // NaN for unused -> all cmps false
        int   ix = (int)v.y;
        if ((d2 < bd[KNN - 1]) || (d2 == bd[KNN - 1] && ix < bi[KNN - 1])) {
            bool c[KNN];
#pragma unroll
            for (int m = 0; m < KNN; ++m) c[m] = (d2 < bd[m]) || (d2 == bd[m] && ix < bi[m]);
#pragma unroll
            for (int m = KNN - 1; m > 0; --m) {
                bd[m] = c[m] ? (c[m - 1] ? bd[m - 1] : d2) : bd[m];
                bi[m] = c[m] ? (c[m - 1] ? bi[m - 1] : ix) : bi[m];
            }
            bd[0] = c[0] ? d2 : bd[0];
            bi[0] = c[0] ? ix : bi[0];
        }
    }
    const int b = q >> 12;
    int* o = nbr + (size_t)q * KNN;
#pragma unroll
    for (int m = 0; m < KNN; ++m) o[m] = (b << 12) + bi[m];
}

// ---------------------------------------------------------------- W pre-permute
__global__ __launch_bounds__(256) void wprep(const float* __restrict__ Wc,
                                             const float* __restrict__ W1,
                                             unsigned* __restrict__ whi,
                                             unsigned* __restrict__ wlo)
{
    const int m = blockIdx.x;
    const float* W = (m < 4) ? (Wc + m * 16384) : W1;
    unsigned* oh = whi + m * 8192;
    unsigned* ol = wlo + m * 8192;
    for (int u = threadIdx.x; u < 8192; u += 256) {
        int kk = u >> 11, ct = (u >> 8) & 7, l = (u >> 2) & 63, d = u & 3;
        int k0 = kk * 32 + ((l >> 4) << 3) + 2 * d;
        int c  = ct * 16 + (l & 15);
        float f0 = W[k0 * 128 + c], f1 = W[(k0 + 1) * 128 + c];
        unsigned h0 = bf16_rne(f0), h1 = bf16_rne(f1);
        float r0 = f0 - bf2f(h0), r1 = f1 - bf2f(h1);
        oh[u] = h0 | (h1 << 16);
        ol[u] = bf16_rne(r0) | (bf16_rne(r1) << 16);
    }
}

// ---------------------------------------------------------------- x0 = relu(pos@W0+b0)
__global__ __launch_bounds__(256) void x0_kernel(const float* __restrict__ pos,
                                                 const float* __restrict__ W0,
                                                 const float* __restrict__ b0,
                                                 float* __restrict__ x0)
{
    int gid = blockIdx.x * 256 + threadIdx.x;
    int node = gid >> 5, qd = gid & 31;
    float px = pos[node * 3 + 0], py = pos[node * 3 + 1], pz = pos[node * 3 + 2];
    const float4 w0 = ((const float4*)W0)[qd];
    const float4 w1 = ((const float4*)W0)[32 + qd];
    const float4 w2 = ((const float4*)W0)[64 + qd];
    const float4 bb = ((const float4*)b0)[qd];
    float4 r;
    r.x = relu_f(fmaf(pz, w2.x, fmaf(py, w1.x, fmaf(px, w0.x, bb.x))));
    r.y = relu_f(fmaf(pz, w2.y, fmaf(py, w1.y, fmaf(px, w0.y, bb.y))));
    r.z = relu_f(fmaf(pz, w2.z, fmaf(py, w1.z, fmaf(px, w0.z, bb.z))));
    r.w = relu_f(fmaf(pz, w2.w, fmaf(py, w1.w, fmaf(px, w0.w, bb.w))));
    ((float4*)x0)[gid] = r;
}

// ---------------------------------------------------------------- MFMA GEMM step
__device__ __forceinline__ void gemm_kk(const float* shrow, const unsigned* sB,
                                        int l, f32x4* acc)
{
    float f[8];
#pragma unroll
    for (int j = 0; j < 8; ++j) f[j] = shrow[j];
    unsigned ah[4], al[4];
#pragma unroll
    for (int d = 0; d < 4; ++d) {
        unsigned h0 = bf16_rne(f[2 * d]), h1 = bf16_rne(f[2 * d + 1]);
        ah[d] = h0 | (h1 << 16);
        float r0 = f[2 * d] - bf2f(h0), r1 = f[2 * d + 1] - bf2f(h1);
        al[d] = bf16_rne(r0) | (bf16_rne(r1) << 16);
    }
    i32x4 ahv = { (int)ah[0], (int)ah[1], (int)ah[2], (int)ah[3] };
    i32x4 alv = { (int)al[0], (int)al[1], (int)al[2], (int)al[3] };
    s16x8 Ah = __builtin_bit_cast(s16x8, ahv);
    s16x8 Al = __builtin_bit_cast(s16x8, alv);
#pragma unroll
    for (int ct = 0; ct < 8; ++ct) {
        i32x4 bh = *(const i32x4*)&sB[(ct * 64 + l) * 4];
        i32x4 bl = *(const i32x4*)&sB[2048 + (ct * 64 + l) * 4];
        s16x8 Bh = __builtin_bit_cast(s16x8, bh);
        s16x8 Bl = __builtin_bit_cast(s16x8, bl);
        acc[ct] = __builtin_amdgcn_mfma_f32_16x16x32_bf16(Ah, Bh, acc[ct], 0, 0, 0);
        acc[ct] = __builtin_amdgcn_mfma_f32_16x16x32_bf16(Al, Bh, acc[ct], 0, 0, 0);
        acc[ct] = __builtin_amdgcn_mfma_f32_16x16x32_bf16(Ah, Bl, acc[ct], 0, 0, 0);
    }
}

// ---------------------------------------------------------------- fused GCN2 layer (MFMA)
__global__ __launch_bounds__(256) void gcn_layer(const float* __restrict__ xin,
                                                 float* __restrict__ xout,
                                                 const float* __restrict__ pos,
                                                 const float* __restrict__ W0,
                                                 const float* __restrict__ b0,
                                                 const unsigned* __restrict__ whi,
                                                 const unsigned* __restrict__ wlo,
                                                 const int* __restrict__ nbr,
                                                 float omb, float beta)
{
    __shared__ float sh[64][129];
    __shared__ __align__(16) unsigned sB[4096];
    __shared__ float sW0[512];
    const int t = threadIdx.x;
    const int bid = blockIdx.x;
    const int swz = (bid & 7) * 128 + (bid >> 3);
    const int node0 = swz * 64;

    if (t < 128) {
        sW0[t] = W0[t]; sW0[128 + t] = W0[128 + t];
        sW0[256 + t] = W0[256 + t]; sW0[384 + t] = b0[t];
    }
    __syncthreads();

    const float4* xin4 = (const float4*)xin;
    for (int u = t; u < 64 * 32; u += 256) {
        int n = u >> 5, qd = u & 31;
        int node = node0 + n;
        float ax = 0.f, ay = 0.f, az = 0.f, aw = 0.f;
        const int* nb = nbr + node * KNN;
#pragma unroll
        for (int k = 0; k < KNN; ++k) {
            float4 v = xin4[nb[k] * 32 + qd];
            ax += v.x; ay += v.y; az += v.z; aw += v.w;
        }
        float px = pos[node * 3 + 0], py = pos[node * 3 + 1], pz = pos[node * 3 + 2];
        int c = qd * 4;
        sh[n][c + 0] = fmaf(0.9f, ax, 0.1f * relu_f(fmaf(pz, sW0[256 + c + 0], fmaf(py, sW0[128 + c + 0], fmaf(px, sW0[c + 0], sW0[384 + c + 0])))));
        sh[n][c + 1] = fmaf(0.9f, ay, 0.1f * relu_f(fmaf(pz, sW0[256 + c + 1], fmaf(py, sW0[128 + c + 1], fmaf(px, sW0[c + 1], sW0[384 + c + 1])))));
        sh[n][c + 2] = fmaf(0.9f, az, 0.1f * relu_f(fmaf(pz, sW0[256 + c + 2], fmaf(py, sW0[128 + c + 2], fmaf(px, sW0[c + 2], sW0[384 + c + 2])))));
        sh[n][c + 3] = fmaf(0.9f, aw, 0.1f * relu_f(fmaf(pz, sW0[256 + c + 3], fmaf(py, sW0[128 + c + 3], fmaf(px, sW0[c + 3], sW0[384 + c + 3])))));
    }

    const int w = t >> 6, l = t & 63, lr = l & 15, lg = l >> 4;
    f32x4 acc[8];
    const f32x4 z4 = { 0.f, 0.f, 0.f, 0.f };
#pragma unroll
    for (int ct = 0; ct < 8; ++ct) acc[ct] = z4;

    for (int kk = 0; kk < 4; ++kk) {
        __syncthreads();
        const uint4* srch = (const uint4*)(whi + kk * 2048);
        const uint4* srcl = (const uint4*)(wlo + kk * 2048);
        uint4* dst = (uint4*)sB;
        dst[t] = srch[t];           dst[256 + t] = srch[256 + t];
        dst[512 + t] = srcl[t];     dst[768 + t] = srcl[256 + t];
        __syncthreads();
        gemm_kk(&sh[w * 16 + lr][kk * 32 + lg * 8], sB, l, acc);
    }

#pragma unroll
    for (int ct = 0; ct < 8; ++ct) {
        int col = ct * 16 + lr;
#pragma unroll
        for (int r = 0; r < 4; ++r) {
            int rw = w * 16 + lg * 4 + r;
            float h = sh[rw][col];
            xout[(size_t)(node0 + rw) * HDIM + col] = relu_f(fmaf(omb, h, beta * acc[ct][r]));
        }
    }
}

// ---------------------------------------------------------------- w1 + max-pool (MFMA)
__global__ __launch_bounds__(256) void w1pool_kernel(const float* __restrict__ xin,
                                                     const unsigned* __restrict__ whi,
                                                     const unsigned* __restrict__ wlo,
                                                     const float* __restrict__ b1,
                                                     unsigned int* __restrict__ pool)
{
    __shared__ float sh[64][129];
    __shared__ __align__(16) unsigned sB[4096];
    __shared__ float smax[16][128];
    const int t = threadIdx.x;
    const int bid = blockIdx.x;
    const int swz = (bid & 7) * 128 + (bid >> 3);
    const int node0 = swz * 64;

    const float4* xin4 = (const float4*)xin;
    for (int u = t; u < 64 * 32; u += 256) {
        int n = u >> 5, qd = u & 31;
        float4 v = xin4[(node0 + n) * 32 + qd];
        int c = qd * 4;
        sh[n][c + 0] = v.x; sh[n][c + 1] = v.y; sh[n][c + 2] = v.z; sh[n][c + 3] = v.w;
    }

    const int w = t >> 6, l = t & 63, lr = l & 15, lg = l >> 4;
    f32x4 acc[8];
    const f32x4 z4 = { 0.f, 0.f, 0.f, 0.f };
#pragma unroll
    for (int ct = 0; ct < 8; ++ct) acc[ct] = z4;

    for (int kk = 0; kk < 4; ++kk) {
        __syncthreads();
        const uint4* srch = (const uint4*)(whi + kk * 2048);
        const uint4* srcl = (const uint4*)(wlo + kk * 2048);
        uint4* dst = (uint4*)sB;
        dst[t] = srch[t];           dst[256 + t] = srch[256 + t];
        dst[512 + t] = srcl[t];     dst[768 + t] = srcl[256 + t];
        __syncthreads();
        gemm_kk(&sh[w * 16 + lr][kk * 32 + lg * 8], sB, l, acc);
    }

#pragma unroll
    for (int ct = 0; ct < 8; ++ct) {
        int col = ct * 16 + lr;
        float m = fmaxf(fmaxf(acc[ct][0], acc[ct][1]), fmaxf(acc[ct][2], acc[ct][3]));
        smax[w * 4 + lg][col] = m + b1[col];
    }
    __syncthreads();
    if (t < 128) {
        float m = smax[0][t];
#pragma unroll
        for (int r = 1; r < 16; ++r) m = fmaxf(m, smax[r][t]);
        unsigned int u = __float_as_uint(m);
        unsigned int key = (u & 0x80000000u) ? ~u : (u | 0x80000000u);
        atomicMax(&pool[(node0 >> 12) * HDIM + t], key);
    }
}

// ---------------------------------------------------------------- MLP head (1 block)
__global__ __launch_bounds__(256) void head_kernel(const unsigned int* __restrict__ pool,
                                                   const float* __restrict__ Wm1, const float* __restrict__ bm1,
                                                   const float* __restrict__ g1,  const float* __restrict__ be1,
                                                   const float* __restrict__ Wm2, const float* __restrict__ bm2,
                                                   const float* __restrict__ g2,  const float* __restrict__ be2,
                                                   const float* __restrict__ Wout,const float* __restrict__ bout,
                                                   float* __restrict__ out)
{
    __shared__ float sA[16][128];
    __shared__ float sB2[16][128];
    __shared__ float sL[16][10];
    const int t = threadIdx.x;
    for (int u = t; u < 2048; u += 256) {
        unsigned int k = pool[u];
        unsigned int orig = (k & 0x80000000u) ? (k ^ 0x80000000u) : ~k;
        sA[u >> 7][u & 127] = __uint_as_float(orig);
    }
    __syncthreads();

    if (t < 128) {
        float y[16];
#pragma unroll
        for (int b = 0; b < 16; ++b) y[b] = bm1[t];
        for (int i = 0; i < 128; ++i) {
            float w = Wm1[i * 128 + t];
#pragma unroll
            for (int b = 0; b < 16; ++b) y[b] = fmaf(sA[b][i], w, y[b]);
        }
        float mu = 0.f;
#pragma unroll
        for (int b = 0; b < 16; ++b) mu += y[b];
        mu *= (1.f / 16.f);
        float var = 0.f;
#pragma unroll
        for (int b = 0; b < 16; ++b) { float d = y[b] - mu; var = fmaf(d, d, var); }
        var *= (1.f / 16.f);
        float sc = g1[t] / sqrtf(var + 1e-5f);
        float sb = be1[t];
#pragma unroll
        for (int b = 0; b < 16; ++b) sB2[b][t] = relu_f((y[b] - mu) * sc + sb);
    }
    __syncthreads();

    if (t < 128) {
        float y[16];
#pragma unroll
        for (int b = 0; b < 16; ++b) y[b] = bm2[t];
        for (int i = 0; i < 128; ++i) {
            float w = Wm2[i * 128 + t];
#pragma unroll
            for (int b = 0; b < 16; ++b) y[b] = fmaf(sB2[b][i], w, y[b]);
        }
        float mu = 0.f;
#pragma unroll
        for (int b = 0; b < 16; ++b) mu += y[b];
        mu *= (1.f / 16.f);
        float var = 0.f;
#pragma unroll
        for (int b = 0; b < 16; ++b) { float d = y[b] - mu; var = fmaf(d, d, var); }
        var *= (1.f / 16.f);
        float sc = g2[t] / sqrtf(var + 1e-5f);
        float sb = be2[t];
#pragma unroll
        for (int b = 0; b < 16; ++b) sA[b][t] = relu_f((y[b] - mu) * sc + sb);
    }
    __syncthreads();

    if (t < 160) {
        int b = t / 10, o = t % 10;
        float a = bout[o];
        for (int i = 0; i < 128; ++i) a = fmaf(sA[b][i], Wout[i * 10 + o], a);
        sL[b][o] = a;
    }
    __syncthreads();

    if (t < 16) {
        float m = sL[t][0];
#pragma unroll
        for (int o = 1; o < 10; ++o) m = fmaxf(m, sL[t][o]);
        float s = 0.f;
#pragma unroll
        for (int o = 0; o < 10; ++o) s += expf(sL[t][o] - m);
        float ls = logf(s);
#pragma unroll
        for (int o = 0; o < 10; ++o) out[t * 10 + o] = sL[t][o] - m - ls;
    }
}

// ----------------------------------------------------------------
extern "C" void kernel_launch(void* const* d_in, const int* in_sizes, int n_in,
                              void* d_out, int out_size, void* d_ws, size_t ws_size,
                              hipStream_t stream)
{
    const float* pos = (const float*)d_in[0];
    const float* W0  = (const float*)d_in[1];
    const float* b0  = (const float*)d_in[2];
    const float* Wc  = (const float*)d_in[3];
    const float* W1  = (const float*)d_in[4];
    const float* b1  = (const float*)d_in[5];
    const float* Wm1 = (const float*)d_in[6];
    const float* bm1 = (const float*)d_in[7];
    const float* g1  = (const float*)d_in[8];
    const float* be1 = (const float*)d_in[9];
    const float* Wm2 = (const float*)d_in[10];
    const float* bm2 = (const float*)d_in[11];
    const float* g2  = (const float*)d_in[12];
    const float* be2 = (const float*)d_in[13];
    const float* Wout= (const float*)d_in[14];
    const float* bout= (const float*)d_in[15];
    float* out = (float*)d_out;

    char* ws = (char*)d_ws;
    float*        xA   = (float*)ws;                       // 33,554,432 B
    float*        xB   = (float*)(ws + 33554432);          // 33,554,432 B
    int*          nbr  = (int*)(ws + 67108864);            //  2,621,440 B
    unsigned int* pool = (unsigned int*)(ws + 69730304);   //      8,192 B
    unsigned*     whi  = (unsigned*)(ws + 69738496);       //    163,840 B
    unsigned*     wlo  = (unsigned*)(ws + 69902336);       //    163,840 B
    // KNN scratch: aliases xA (pdi) and xB (grid data) -- all dead before x0/gcn.
    uint2*    pdi    = (uint2*)ws;                         // 25,165,824 B @0
    float4*   sPt    = (float4*)(ws + 33554432);           //  1,048,576 B
    unsigned* sIdx   = (unsigned*)(ws + 34603008);         //    262,144 B
    unsigned* startb = (unsigned*)(ws + 34865152);         //     32,768 B
    unsigned* cursor = (unsigned*)(ws + 35127296);         //     32,768 B
    unsigned* hist   = (unsigned*)(ws + 35389440);         //     32,768 B
    float*    bboxb  = (float*)(ws + 35651584);            //        384 B

    bbox_kernel<<<16, 256, 0, stream>>>(pos, bboxb);
    hipMemsetAsync(hist, 0, 16 * NCELL * sizeof(unsigned), stream);
    bin_count<<<256, 256, 0, stream>>>(pos, bboxb, hist);
    bin_scan<<<16, 256, 0, stream>>>(hist, startb, cursor);
    bin_scatter<<<256, 256, 0, stream>>>(pos, bboxb, cursor, sPt, sIdx);
    hipMemsetAsync(pdi, 0xFF, (size_t)16 * NPTS * NSPLIT * SLOTS * 8, stream);
    wprep<<<5, 256, 0, stream>>>(Wc, W1, whi, wlo);
    knn_grid<<<1024, 256, 0, stream>>>(sPt, sIdx, startb, bboxb, pdi);
    knn_merge<<<256, 256, 0, stream>>>(pdi, nbr);
    x0_kernel<<<8192, 256, 0, stream>>>(pos, W0, b0, xA);

    const float betas[4] = { 0.40546510810816438f, 0.22314355131420976f,
                             0.15415067982725836f, 0.11778303565638346f };
    gcn_layer<<<1024, 256, 0, stream>>>(xA, xB, pos, W0, b0, whi + 0 * 8192, wlo + 0 * 8192, nbr, 1.f - betas[0], betas[0]);
    gcn_layer<<<1024, 256, 0, stream>>>(xB, xA, pos, W0, b0, whi + 1 * 8192, wlo + 1 * 8192, nbr, 1.f - betas[1], betas[1]);
    gcn_layer<<<1024, 256, 0, stream>>>(xA, xB, pos, W0, b0, whi + 2 * 8192, wlo + 2 * 8192, nbr, 1.f - betas[2], betas[2]);
    gcn_layer<<<1024, 256, 0, stream>>>(xB, xA, pos, W0, b0, whi + 3 * 8192, wlo + 3 * 8192, nbr, 1.f - betas[3], betas[3]);

    hipMemsetAsync(pool, 0, 16 * HDIM * sizeof(unsigned int), stream);
    w1pool_kernel<<<1024, 256, 0, stream>>>(xA, whi + 4 * 8192, wlo + 4 * 8192, b1, pool);
    head_kernel<<<1, 256, 0, stream>>>(pool, Wm1, bm1, g1, be1, Wm2, bm2, g2, be2, Wout, bout, out);
}

// Round 11
// 527.679 us; speedup vs baseline: 6.9646x; 4.3560x over previous
//
#include <hip/hip_runtime.h>
#include <math.h>

#define NPTS 4096
#define HDIM 128
#define KNN 10
#define NSPLIT 8
#define CTILE 512
#define SLOTS 12

typedef __attribute__((ext_vector_type(4))) float f32x4;
typedef __attribute__((ext_vector_type(4))) int   i32x4;
typedef __attribute__((ext_vector_type(8))) short s16x8;

__device__ __forceinline__ float relu_f(float x) { return x > 0.f ? x : 0.f; }
__device__ __forceinline__ float med3_f(float a, float b, float c) {
    return __builtin_amdgcn_fmed3f(a, b, c);
}
__device__ __forceinline__ unsigned bf16_rne(float f) {
    unsigned u = __float_as_uint(f);
    return (u + 0x7fffu + ((u >> 16) & 1u)) >> 16;
}
__device__ __forceinline__ float bf2f(unsigned h) { return __uint_as_float(h << 16); }

// ---------------------------------------------------------------- KNN partial
// grid: 16 graphs x 16 query-chunks x 8 candidate-splits = 2048 blocks, 256 thr.
// 8 KB LDS -> 8 blocks/CU (100% wave cap vs R7's 50%). Same total work.
// Pass 1: top-10 DISTANCES via med3 network (branch-free). Pass 2: rescan with
// threshold bd[9], emit (d2,idx); unused slots NaN-padded here (no memset).
// Distance arithmetic bit-identical to the verified R0-R7 kernels; splits
// visited ascending = global-index-ascending -> stable tie-break preserved.
__global__ __launch_bounds__(256) void knn_part(const float* __restrict__ pos,
                                                uint2* __restrict__ pdi)
{
    __shared__ float4 spt[CTILE];                      // 8 KB
    const int bid = blockIdx.x;
    const int s = bid & 7;
    const int chunk = (bid >> 3) & 15;
    const int b = bid >> 7;
    const float* pb = pos + (size_t)b * NPTS * 3;
    const int c0 = s << 9;

    for (int j = threadIdx.x; j < CTILE; j += 256) {
        int g = c0 + j;
        float x = pb[3 * g + 0], y = pb[3 * g + 1], z = pb[3 * g + 2];
        float sq = __fadd_rn(__fadd_rn(__fmul_rn(x, x), __fmul_rn(y, y)), __fmul_rn(z, z));
        spt[j] = make_float4(x, y, z, sq);
    }
    __syncthreads();

    const int i = chunk * 256 + threadIdx.x;
    const float qx = pb[3 * i + 0], qy = pb[3 * i + 1], qz = pb[3 * i + 2];
    const float qw = __fadd_rn(__fadd_rn(__fmul_rn(qx, qx), __fmul_rn(qy, qy)), __fmul_rn(qz, qz));

    float bd[KNN];
#pragma unroll
    for (int m = 0; m < KNN; ++m) bd[m] = INFINITY;

#pragma unroll 4
    for (int j = 0; j < CTILE; ++j) {
        float4 p = spt[j];
        float dot = __fadd_rn(__fadd_rn(__fmul_rn(qx, p.x), __fmul_rn(qy, p.y)),
                              __fmul_rn(qz, p.z));
        float d2 = __fsub_rn(__fadd_rn(qw, p.w), __fmul_rn(2.f, dot));
#pragma unroll
        for (int m = KNN - 1; m > 0; --m) bd[m] = med3_f(d2, bd[m - 1], bd[m]);
        bd[0] = fminf(d2, bd[0]);
    }
    const float thr = bd[KNN - 1];                     // 10th smallest in this split

    uint2* o = pdi + ((size_t)(b * NPTS + i) * NSPLIT + s) * SLOTS;
    int cnt = 0;
#pragma unroll 4
    for (int j = 0; j < CTILE; ++j) {
        float4 p = spt[j];
        float dot = __fadd_rn(__fadd_rn(__fmul_rn(qx, p.x), __fmul_rn(qy, p.y)),
                              __fmul_rn(qz, p.z));
        float d2 = __fsub_rn(__fadd_rn(qw, p.w), __fmul_rn(2.f, dot));
        if (d2 <= thr && cnt < SLOTS) {
            o[cnt] = make_uint2(__float_as_uint(d2), (unsigned)(c0 + j));
            ++cnt;
        }
    }
    for (; cnt < SLOTS; ++cnt)                          // NaN pad (replaces memset)
        o[cnt] = make_uint2(0xFFFFFFFFu, 0u);
}

// ---------------------------------------------------------------- KNN merge
// 8*SLOTS=96 candidates per query, visited split-ascending then index-ascending
// (= global-index-ascending); NaN entries fail the < compare. Stable
// lower-index tie-break identical to a full scan.
__global__ __launch_bounds__(256) void knn_merge(const uint2* __restrict__ pdi,
                                                 int* __restrict__ nbr)
{
    const int q = blockIdx.x * 256 + threadIdx.x;      // 0..65535
    const uint2* in = pdi + (size_t)q * (NSPLIT * SLOTS);
    float bd[KNN];
    int   bi[KNN];
#pragma unroll
    for (int m = 0; m < KNN; ++m) { bd[m] = 3.4e38f; bi[m] = 0; }
#pragma unroll 4
    for (int u = 0; u < NSPLIT * SLOTS; ++u) {
        uint2 v = in[u];
        float d2 = __uint_as_float(v.x);               // NaN for unused -> all cmps false
        int   ix = (int)v.y;
        if (d2 < bd[KNN - 1]) {
            bool c[KNN];
#pragma unroll
            for (int m = 0; m < KNN; ++m) c[m] = d2 < bd[m];
#pragma unroll
            for (int m = KNN - 1; m > 0; --m) {
                bd[m] = c[m] ? (c[m - 1] ? bd[m - 1] : d2) : bd[m];
                bi[m] = c[m] ? (c[m - 1] ? bi[m - 1] : ix) : bi[m];
            }
            bd[0] = c[0] ? d2 : bd[0];
            bi[0] = c[0] ? ix : bi[0];
        }
    }
    const int b = q >> 12;
    int* o = nbr + (size_t)q * KNN;
#pragma unroll
    for (int m = 0; m < KNN; ++m) o[m] = (b << 12) + bi[m];
}

// ---------------------------------------------------------------- W pre-permute
__global__ __launch_bounds__(256) void wprep(const float* __restrict__ Wc,
                                             const float* __restrict__ W1,
                                             unsigned* __restrict__ whi,
                                             unsigned* __restrict__ wlo)
{
    const int m = blockIdx.x;
    const float* W = (m < 4) ? (Wc + m * 16384) : W1;
    unsigned* oh = whi + m * 8192;
    unsigned* ol = wlo + m * 8192;
    for (int u = threadIdx.x; u < 8192; u += 256) {
        int kk = u >> 11, ct = (u >> 8) & 7, l = (u >> 2) & 63, d = u & 3;
        int k0 = kk * 32 + ((l >> 4) << 3) + 2 * d;
        int c  = ct * 16 + (l & 15);
        float f0 = W[k0 * 128 + c], f1 = W[(k0 + 1) * 128 + c];
        unsigned h0 = bf16_rne(f0), h1 = bf16_rne(f1);
        float r0 = f0 - bf2f(h0), r1 = f1 - bf2f(h1);
        oh[u] = h0 | (h1 << 16);
        ol[u] = bf16_rne(r0) | (bf16_rne(r1) << 16);
    }
}

// ---------------------------------------------------------------- x0 = relu(pos@W0+b0)
__global__ __launch_bounds__(256) void x0_kernel(const float* __restrict__ pos,
                                                 const float* __restrict__ W0,
                                                 const float* __restrict__ b0,
                                                 float* __restrict__ x0)
{
    int gid = blockIdx.x * 256 + threadIdx.x;
    int node = gid >> 5, qd = gid & 31;
    float px = pos[node * 3 + 0], py = pos[node * 3 + 1], pz = pos[node * 3 + 2];
    const float4 w0 = ((const float4*)W0)[qd];
    const float4 w1 = ((const float4*)W0)[32 + qd];
    const float4 w2 = ((const float4*)W0)[64 + qd];
    const float4 bb = ((const float4*)b0)[qd];
    float4 r;
    r.x = relu_f(fmaf(pz, w2.x, fmaf(py, w1.x, fmaf(px, w0.x, bb.x))));
    r.y = relu_f(fmaf(pz, w2.y, fmaf(py, w1.y, fmaf(px, w0.y, bb.y))));
    r.z = relu_f(fmaf(pz, w2.z, fmaf(py, w1.z, fmaf(px, w0.z, bb.z))));
    r.w = relu_f(fmaf(pz, w2.w, fmaf(py, w1.w, fmaf(px, w0.w, bb.w))));
    ((float4*)x0)[gid] = r;
}

// ---------------------------------------------------------------- MFMA GEMM step
__device__ __forceinline__ void gemm_kk(const float* shrow, const unsigned* sB,
                                        int l, f32x4* acc)
{
    float f[8];
#pragma unroll
    for (int j = 0; j < 8; ++j) f[j] = shrow[j];
    unsigned ah[4], al[4];
#pragma unroll
    for (int d = 0; d < 4; ++d) {
        unsigned h0 = bf16_rne(f[2 * d]), h1 = bf16_rne(f[2 * d + 1]);
        ah[d] = h0 | (h1 << 16);
        float r0 = f[2 * d] - bf2f(h0), r1 = f[2 * d + 1] - bf2f(h1);
        al[d] = bf16_rne(r0) | (bf16_rne(r1) << 16);
    }
    i32x4 ahv = { (int)ah[0], (int)ah[1], (int)ah[2], (int)ah[3] };
    i32x4 alv = { (int)al[0], (int)al[1], (int)al[2], (int)al[3] };
    s16x8 Ah = __builtin_bit_cast(s16x8, ahv);
    s16x8 Al = __builtin_bit_cast(s16x8, alv);
#pragma unroll
    for (int ct = 0; ct < 8; ++ct) {
        i32x4 bh = *(const i32x4*)&sB[(ct * 64 + l) * 4];
        i32x4 bl = *(const i32x4*)&sB[2048 + (ct * 64 + l) * 4];
        s16x8 Bh = __builtin_bit_cast(s16x8, bh);
        s16x8 Bl = __builtin_bit_cast(s16x8, bl);
        acc[ct] = __builtin_amdgcn_mfma_f32_16x16x32_bf16(Ah, Bh, acc[ct], 0, 0, 0);
        acc[ct] = __builtin_amdgcn_mfma_f32_16x16x32_bf16(Al, Bh, acc[ct], 0, 0, 0);
        acc[ct] = __builtin_amdgcn_mfma_f32_16x16x32_bf16(Ah, Bl, acc[ct], 0, 0, 0);
    }
}

// ---------------------------------------------------------------- fused GCN2 layer (MFMA)
__global__ __launch_bounds__(256) void gcn_layer(const float* __restrict__ xin,
                                                 float* __restrict__ xout,
                                                 const float* __restrict__ pos,
                                                 const float* __restrict__ W0,
                                                 const float* __restrict__ b0,
                                                 const unsigned* __restrict__ whi,
                                                 const unsigned* __restrict__ wlo,
                                                 const int* __restrict__ nbr,
                                                 float omb, float beta)
{
    __shared__ float sh[64][129];
    __shared__ __align__(16) unsigned sB[4096];
    __shared__ float sW0[512];
    const int t = threadIdx.x;
    const int bid = blockIdx.x;
    const int swz = (bid & 7) * 128 + (bid >> 3);      // XCD-chunked, bijective
    const int node0 = swz * 64;

    if (t < 128) {
        sW0[t] = W0[t]; sW0[128 + t] = W0[128 + t];
        sW0[256 + t] = W0[256 + t]; sW0[384 + t] = b0[t];
    }
    __syncthreads();

    const float4* xin4 = (const float4*)xin;
    for (int u = t; u < 64 * 32; u += 256) {
        int n = u >> 5, qd = u & 31;
        int node = node0 + n;
        float ax = 0.f, ay = 0.f, az = 0.f, aw = 0.f;
        const int* nb = nbr + node * KNN;
#pragma unroll
        for (int k = 0; k < KNN; ++k) {
            float4 v = xin4[nb[k] * 32 + qd];
            ax += v.x; ay += v.y; az += v.z; aw += v.w;
        }
        float px = pos[node * 3 + 0], py = pos[node * 3 + 1], pz = pos[node * 3 + 2];
        int c = qd * 4;
        sh[n][c + 0] = fmaf(0.9f, ax, 0.1f * relu_f(fmaf(pz, sW0[256 + c + 0], fmaf(py, sW0[128 + c + 0], fmaf(px, sW0[c + 0], sW0[384 + c + 0])))));
        sh[n][c + 1] = fmaf(0.9f, ay, 0.1f * relu_f(fmaf(pz, sW0[256 + c + 1], fmaf(py, sW0[128 + c + 1], fmaf(px, sW0[c + 1], sW0[384 + c + 1])))));
        sh[n][c + 2] = fmaf(0.9f, az, 0.1f * relu_f(fmaf(pz, sW0[256 + c + 2], fmaf(py, sW0[128 + c + 2], fmaf(px, sW0[c + 2], sW0[384 + c + 2])))));
        sh[n][c + 3] = fmaf(0.9f, aw, 0.1f * relu_f(fmaf(pz, sW0[256 + c + 3], fmaf(py, sW0[128 + c + 3], fmaf(px, sW0[c + 3], sW0[384 + c + 3])))));
    }

    const int w = t >> 6, l = t & 63, lr = l & 15, lg = l >> 4;
    f32x4 acc[8];
    const f32x4 z4 = { 0.f, 0.f, 0.f, 0.f };
#pragma unroll
    for (int ct = 0; ct < 8; ++ct) acc[ct] = z4;

    for (int kk = 0; kk < 4; ++kk) {
        __syncthreads();
        const uint4* srch = (const uint4*)(whi + kk * 2048);
        const uint4* srcl = (const uint4*)(wlo + kk * 2048);
        uint4* dst = (uint4*)sB;
        dst[t] = srch[t];           dst[256 + t] = srch[256 + t];
        dst[512 + t] = srcl[t];     dst[768 + t] = srcl[256 + t];
        __syncthreads();
        gemm_kk(&sh[w * 16 + lr][kk * 32 + lg * 8], sB, l, acc);
    }

#pragma unroll
    for (int ct = 0; ct < 8; ++ct) {
        int col = ct * 16 + lr;
#pragma unroll
        for (int r = 0; r < 4; ++r) {
            int rw = w * 16 + lg * 4 + r;
            float h = sh[rw][col];
            xout[(size_t)(node0 + rw) * HDIM + col] = relu_f(fmaf(omb, h, beta * acc[ct][r]));
        }
    }
}

// ---------------------------------------------------------------- w1 + max-pool (MFMA)
__global__ __launch_bounds__(256) void w1pool_kernel(const float* __restrict__ xin,
                                                     const unsigned* __restrict__ whi,
                                                     const unsigned* __restrict__ wlo,
                                                     const float* __restrict__ b1,
                                                     unsigned int* __restrict__ pool)
{
    __shared__ float sh[64][129];
    __shared__ __align__(16) unsigned sB[4096];
    __shared__ float smax[16][128];
    const int t = threadIdx.x;
    const int bid = blockIdx.x;
    const int swz = (bid & 7) * 128 + (bid >> 3);
    const int node0 = swz * 64;

    const float4* xin4 = (const float4*)xin;
    for (int u = t; u < 64 * 32; u += 256) {
        int n = u >> 5, qd = u & 31;
        float4 v = xin4[(node0 + n) * 32 + qd];
        int c = qd * 4;
        sh[n][c + 0] = v.x; sh[n][c + 1] = v.y; sh[n][c + 2] = v.z; sh[n][c + 3] = v.w;
    }

    const int w = t >> 6, l = t & 63, lr = l & 15, lg = l >> 4;
    f32x4 acc[8];
    const f32x4 z4 = { 0.f, 0.f, 0.f, 0.f };
#pragma unroll
    for (int ct = 0; ct < 8; ++ct) acc[ct] = z4;

    for (int kk = 0; kk < 4; ++kk) {
        __syncthreads();
        const uint4* srch = (const uint4*)(whi + kk * 2048);
        const uint4* srcl = (const uint4*)(wlo + kk * 2048);
        uint4* dst = (uint4*)sB;
        dst[t] = srch[t];           dst[256 + t] = srch[256 + t];
        dst[512 + t] = srcl[t];     dst[768 + t] = srcl[256 + t];
        __syncthreads();
        gemm_kk(&sh[w * 16 + lr][kk * 32 + lg * 8], sB, l, acc);
    }

#pragma unroll
    for (int ct = 0; ct < 8; ++ct) {
        int col = ct * 16 + lr;
        float m = fmaxf(fmaxf(acc[ct][0], acc[ct][1]), fmaxf(acc[ct][2], acc[ct][3]));
        smax[w * 4 + lg][col] = m + b1[col];
    }
    __syncthreads();
    if (t < 128) {
        float m = smax[0][t];
#pragma unroll
        for (int r = 1; r < 16; ++r) m = fmaxf(m, smax[r][t]);
        unsigned int u = __float_as_uint(m);
        unsigned int key = (u & 0x80000000u) ? ~u : (u | 0x80000000u);
        atomicMax(&pool[(node0 >> 12) * HDIM + t], key);
    }
}

// ---------------------------------------------------------------- MLP head (1 block)
__global__ __launch_bounds__(256) void head_kernel(const unsigned int* __restrict__ pool,
                                                   const float* __restrict__ Wm1, const float* __restrict__ bm1,
                                                   const float* __restrict__ g1,  const float* __restrict__ be1,
                                                   const float* __restrict__ Wm2, const float* __restrict__ bm2,
                                                   const float* __restrict__ g2,  const float* __restrict__ be2,
                                                   const float* __restrict__ Wout,const float* __restrict__ bout,
                                                   float* __restrict__ out)
{
    __shared__ float sA[16][128];
    __shared__ float sB2[16][128];
    __shared__ float sL[16][10];
    const int t = threadIdx.x;
    for (int u = t; u < 2048; u += 256) {
        unsigned int k = pool[u];
        unsigned int orig = (k & 0x80000000u) ? (k ^ 0x80000000u) : ~k;
        sA[u >> 7][u & 127] = __uint_as_float(orig);
    }
    __syncthreads();

    if (t < 128) {
        float y[16];
#pragma unroll
        for (int b = 0; b < 16; ++b) y[b] = bm1[t];
        for (int i = 0; i < 128; ++i) {
            float w = Wm1[i * 128 + t];
#pragma unroll
            for (int b = 0; b < 16; ++b) y[b] = fmaf(sA[b][i], w, y[b]);
        }
        float mu = 0.f;
#pragma unroll
        for (int b = 0; b < 16; ++b) mu += y[b];
        mu *= (1.f / 16.f);
        float var = 0.f;
#pragma unroll
        for (int b = 0; b < 16; ++b) { float d = y[b] - mu; var = fmaf(d, d, var); }
        var *= (1.f / 16.f);
        float sc = g1[t] / sqrtf(var + 1e-5f);
        float sb = be1[t];
#pragma unroll
        for (int b = 0; b < 16; ++b) sB2[b][t] = relu_f((y[b] - mu) * sc + sb);
    }
    __syncthreads();

    if (t < 128) {
        float y[16];
#pragma unroll
        for (int b = 0; b < 16; ++b) y[b] = bm2[t];
        for (int i = 0; i < 128; ++i) {
            float w = Wm2[i * 128 + t];
#pragma unroll
            for (int b = 0; b < 16; ++b) y[b] = fmaf(sB2[b][i], w, y[b]);
        }
        float mu = 0.f;
#pragma unroll
        for (int b = 0; b < 16; ++b) mu += y[b];
        mu *= (1.f / 16.f);
        float var = 0.f;
#pragma unroll
        for (int b = 0; b < 16; ++b) { float d = y[b] - mu; var = fmaf(d, d, var); }
        var *= (1.f / 16.f);
        float sc = g2[t] / sqrtf(var + 1e-5f);
        float sb = be2[t];
#pragma unroll
        for (int b = 0; b < 16; ++b) sA[b][t] = relu_f((y[b] - mu) * sc + sb);
    }
    __syncthreads();

    if (t < 160) {
        int b = t / 10, o = t % 10;
        float a = bout[o];
        for (int i = 0; i < 128; ++i) a = fmaf(sA[b][i], Wout[i * 10 + o], a);
        sL[b][o] = a;
    }
    __syncthreads();

    if (t < 16) {
        float m = sL[t][0];
#pragma unroll
        for (int o = 1; o < 10; ++o) m = fmaxf(m, sL[t][o]);
        float s = 0.f;
#pragma unroll
        for (int o = 0; o < 10; ++o) s += expf(sL[t][o] - m);
        float ls = logf(s);
#pragma unroll
        for (int o = 0; o < 10; ++o) out[t * 10 + o] = sL[t][o] - m - ls;
    }
}

// ----------------------------------------------------------------
extern "C" void kernel_launch(void* const* d_in, const int* in_sizes, int n_in,
                              void* d_out, int out_size, void* d_ws, size_t ws_size,
                              hipStream_t stream)
{
    const float* pos = (const float*)d_in[0];
    const float* W0  = (const float*)d_in[1];
    const float* b0  = (const float*)d_in[2];
    const float* Wc  = (const float*)d_in[3];
    const float* W1  = (const float*)d_in[4];
    const float* b1  = (const float*)d_in[5];
    const float* Wm1 = (const float*)d_in[6];
    const float* bm1 = (const float*)d_in[7];
    const float* g1  = (const float*)d_in[8];
    const float* be1 = (const float*)d_in[9];
    const float* Wm2 = (const float*)d_in[10];
    const float* bm2 = (const float*)d_in[11];
    const float* g2  = (const float*)d_in[12];
    const float* be2 = (const float*)d_in[13];
    const float* Wout= (const float*)d_in[14];
    const float* bout= (const float*)d_in[15];
    float* out = (float*)d_out;

    char* ws = (char*)d_ws;
    float*        xA   = (float*)ws;                       // 33,554,432 B
    float*        xB   = (float*)(ws + 33554432);          // 33,554,432 B
    int*          nbr  = (int*)(ws + 67108864);            //  2,621,440 B
    unsigned int* pool = (unsigned int*)(ws + 69730304);   //      8,192 B
    unsigned*     whi  = (unsigned*)(ws + 69738496);       //    163,840 B
    unsigned*     wlo  = (unsigned*)(ws + 69902336);       //    163,840 B
    // KNN hit buffer: 16*4096*8*12*8 = 50,331,648 B, aliases xA+xB (dead
    // before x0/gcn write them).
    uint2* pdi = (uint2*)ws;

    wprep<<<5, 256, 0, stream>>>(Wc, W1, whi, wlo);
    knn_part<<<2048, 256, 0, stream>>>(pos, pdi);
    knn_merge<<<256, 256, 0, stream>>>(pdi, nbr);
    x0_kernel<<<8192, 256, 0, stream>>>(pos, W0, b0, xA);

    const float betas[4] = { 0.40546510810816438f, 0.22314355131420976f,
                             0.15415067982725836f, 0.11778303565638346f };
    gcn_layer<<<1024, 256, 0, stream>>>(xA, xB, pos, W0, b0, whi + 0 * 8192, wlo + 0 * 8192, nbr, 1.f - betas[0], betas[0]);
    gcn_layer<<<1024, 256, 0, stream>>>(xB, xA, pos, W0, b0, whi + 1 * 8192, wlo + 1 * 8192, nbr, 1.f - betas[1], betas[1]);
    gcn_layer<<<1024, 256, 0, stream>>>(xA, xB, pos, W0, b0, whi + 2 * 8192, wlo + 2 * 8192, nbr, 1.f - betas[2], betas[2]);
    gcn_layer<<<1024, 256, 0, stream>>>(xB, xA, pos, W0, b0, whi + 3 * 8192, wlo + 3 * 8192, nbr, 1.f - betas[3], betas[3]);

    hipMemsetAsync(pool, 0, 16 * HDIM * sizeof(unsigned int), stream);
    w1pool_kernel<<<1024, 256, 0, stream>>>(xA, whi + 4 * 8192, wlo + 4 * 8192, b1, pool);
    head_kernel<<<1, 256, 0, stream>>>(pool, Wm1, bm1, g1, be1, Wm2, bm2, g2, be2, Wout, bout, out);
}

// Round 12
// 513.312 us; speedup vs baseline: 7.1596x; 1.0280x over previous
//
#include <hip/hip_runtime.h>
#include <math.h>

#define NPTS 4096
#define HDIM 128
#define KNN 10
#define NSPLIT 8
#define CTILE 512
#define SLOTS 12

typedef __attribute__((ext_vector_type(4))) float f32x4;
typedef __attribute__((ext_vector_type(4))) int   i32x4;
typedef __attribute__((ext_vector_type(8))) short s16x8;

__device__ __forceinline__ float relu_f(float x) { return x > 0.f ? x : 0.f; }
__device__ __forceinline__ float med3_f(float a, float b, float c) {
    return __builtin_amdgcn_fmed3f(a, b, c);
}
__device__ __forceinline__ unsigned bf16_rne(float f) {
    unsigned u = __float_as_uint(f);
    return (u + 0x7fffu + ((u >> 16) & 1u)) >> 16;
}
__device__ __forceinline__ float bf2f(unsigned h) { return __uint_as_float(h << 16); }

// ---------------------------------------------------------------- KNN partial
// grid: 16 graphs x 16 query-chunks x 8 candidate-splits = 2048 blocks, 256 thr.
// Key trick: rank by e = q.p - |p|^2/2 (descending) == d2 ascending, since
// d2 = |q|^2 - 2e exactly. Pre-storing -|p|^2/2 in spt.w makes e a 3-FMA
// chain (vs 8-instr distance). Top-10 via med3 max-network (branch-free).
// Pass 2 rescans with threshold thr = 10th-largest e, emits (e_bits, idx);
// unused slots NaN-padded. Selection deviates from exact-d2 ranking only for
// candidate pairs with true distances within ~1 ulp (measure-zero).
__global__ __launch_bounds__(256) void knn_part(const float* __restrict__ pos,
                                                uint2* __restrict__ pdi)
{
    __shared__ float4 spt[CTILE];                      // 8 KB
    const int bid = blockIdx.x;
    const int s = bid & 7;
    const int chunk = (bid >> 3) & 15;
    const int b = bid >> 7;
    const float* pb = pos + (size_t)b * NPTS * 3;
    const int c0 = s << 9;

    for (int j = threadIdx.x; j < CTILE; j += 256) {
        int g = c0 + j;
        float x = pb[3 * g + 0], y = pb[3 * g + 1], z = pb[3 * g + 2];
        float sq = __fadd_rn(__fadd_rn(__fmul_rn(x, x), __fmul_rn(y, y)), __fmul_rn(z, z));
        spt[j] = make_float4(x, y, z, __fmul_rn(sq, -0.5f));   // exact pow2 scale
    }
    __syncthreads();

    const int i = chunk * 256 + threadIdx.x;
    const float qx = pb[3 * i + 0], qy = pb[3 * i + 1], qz = pb[3 * i + 2];

    float be[KNN];                                     // top-10 LARGEST e, sorted desc
#pragma unroll
    for (int m = 0; m < KNN; ++m) be[m] = -INFINITY;

#pragma unroll 4
    for (int j = 0; j < CTILE; ++j) {
        float4 p = spt[j];
        float e = fmaf(qz, p.z, fmaf(qy, p.y, fmaf(qx, p.x, p.w)));   // 3 FMA
#pragma unroll
        for (int m = KNN - 1; m > 0; --m) be[m] = med3_f(e, be[m - 1], be[m]);
        be[0] = fmaxf(e, be[0]);
    }
    const float thr = be[KNN - 1];                     // 10th largest e in this split

    uint2* o = pdi + ((size_t)(b * NPTS + i) * NSPLIT + s) * SLOTS;
    int cnt = 0;
#pragma unroll 4
    for (int j = 0; j < CTILE; ++j) {
        float4 p = spt[j];
        float e = fmaf(qz, p.z, fmaf(qy, p.y, fmaf(qx, p.x, p.w)));
        if (e >= thr && cnt < SLOTS) {
            o[cnt] = make_uint2(__float_as_uint(e), (unsigned)(c0 + j));
            ++cnt;
        }
    }
    for (; cnt < SLOTS; ++cnt)                          // NaN pad
        o[cnt] = make_uint2(0xFFFFFFFFu, 0u);
}

// ---------------------------------------------------------------- KNN merge
// 8*SLOTS=96 candidates per query; select 10 LARGEST e, ties -> lower index
// (== lax.top_k stable tie-break on -d2). NaN entries fail all compares.
__global__ __launch_bounds__(256) void knn_merge(const uint2* __restrict__ pdi,
                                                 int* __restrict__ nbr)
{
    const int q = blockIdx.x * 256 + threadIdx.x;      // 0..65535
    const uint2* in = pdi + (size_t)q * (NSPLIT * SLOTS);
    float be[KNN];
    int   bi[KNN];
#pragma unroll
    for (int m = 0; m < KNN; ++m) { be[m] = -3.4e38f; bi[m] = 0x7fffffff; }
#pragma unroll 4
    for (int u = 0; u < NSPLIT * SLOTS; ++u) {
        uint2 v = in[u];
        float e  = __uint_as_float(v.x);               // NaN for unused -> all cmps false
        int   ix = (int)v.y;
        if ((e > be[KNN - 1]) || (e == be[KNN - 1] && ix < bi[KNN - 1])) {
            bool c[KNN];
#pragma unroll
            for (int m = 0; m < KNN; ++m) c[m] = (e > be[m]) || (e == be[m] && ix < bi[m]);
#pragma unroll
            for (int m = KNN - 1; m > 0; --m) {
                be[m] = c[m] ? (c[m - 1] ? be[m - 1] : e) : be[m];
                bi[m] = c[m] ? (c[m - 1] ? bi[m - 1] : ix) : bi[m];
            }
            be[0] = c[0] ? e : be[0];
            bi[0] = c[0] ? ix : bi[0];
        }
    }
    const int b = q >> 12;
    int* o = nbr + (size_t)q * KNN;
#pragma unroll
    for (int m = 0; m < KNN; ++m) o[m] = (b << 12) + bi[m];
}

// ---------------------------------------------------------------- W pre-permute
__global__ __launch_bounds__(256) void wprep(const float* __restrict__ Wc,
                                             const float* __restrict__ W1,
                                             unsigned* __restrict__ whi,
                                             unsigned* __restrict__ wlo)
{
    const int m = blockIdx.x;
    const float* W = (m < 4) ? (Wc + m * 16384) : W1;
    unsigned* oh = whi + m * 8192;
    unsigned* ol = wlo + m * 8192;
    for (int u = threadIdx.x; u < 8192; u += 256) {
        int kk = u >> 11, ct = (u >> 8) & 7, l = (u >> 2) & 63, d = u & 3;
        int k0 = kk * 32 + ((l >> 4) << 3) + 2 * d;
        int c  = ct * 16 + (l & 15);
        float f0 = W[k0 * 128 + c], f1 = W[(k0 + 1) * 128 + c];
        unsigned h0 = bf16_rne(f0), h1 = bf16_rne(f1);
        float r0 = f0 - bf2f(h0), r1 = f1 - bf2f(h1);
        oh[u] = h0 | (h1 << 16);
        ol[u] = bf16_rne(r0) | (bf16_rne(r1) << 16);
    }
}

// ---------------------------------------------------------------- x0 = relu(pos@W0+b0)
__global__ __launch_bounds__(256) void x0_kernel(const float* __restrict__ pos,
                                                 const float* __restrict__ W0,
                                                 const float* __restrict__ b0,
                                                 float* __restrict__ x0)
{
    int gid = blockIdx.x * 256 + threadIdx.x;
    int node = gid >> 5, qd = gid & 31;
    float px = pos[node * 3 + 0], py = pos[node * 3 + 1], pz = pos[node * 3 + 2];
    const float4 w0 = ((const float4*)W0)[qd];
    const float4 w1 = ((const float4*)W0)[32 + qd];
    const float4 w2 = ((const float4*)W0)[64 + qd];
    const float4 bb = ((const float4*)b0)[qd];
    float4 r;
    r.x = relu_f(fmaf(pz, w2.x, fmaf(py, w1.x, fmaf(px, w0.x, bb.x))));
    r.y = relu_f(fmaf(pz, w2.y, fmaf(py, w1.y, fmaf(px, w0.y, bb.y))));
    r.z = relu_f(fmaf(pz, w2.z, fmaf(py, w1.z, fmaf(px, w0.z, bb.z))));
    r.w = relu_f(fmaf(pz, w2.w, fmaf(py, w1.w, fmaf(px, w0.w, bb.w))));
    ((float4*)x0)[gid] = r;
}

// ---------------------------------------------------------------- MFMA GEMM step
__device__ __forceinline__ void gemm_kk(const float* shrow, const unsigned* sB,
                                        int l, f32x4* acc)
{
    float f[8];
#pragma unroll
    for (int j = 0; j < 8; ++j) f[j] = shrow[j];
    unsigned ah[4], al[4];
#pragma unroll
    for (int d = 0; d < 4; ++d) {
        unsigned h0 = bf16_rne(f[2 * d]), h1 = bf16_rne(f[2 * d + 1]);
        ah[d] = h0 | (h1 << 16);
        float r0 = f[2 * d] - bf2f(h0), r1 = f[2 * d + 1] - bf2f(h1);
        al[d] = bf16_rne(r0) | (bf16_rne(r1) << 16);
    }
    i32x4 ahv = { (int)ah[0], (int)ah[1], (int)ah[2], (int)ah[3] };
    i32x4 alv = { (int)al[0], (int)al[1], (int)al[2], (int)al[3] };
    s16x8 Ah = __builtin_bit_cast(s16x8, ahv);
    s16x8 Al = __builtin_bit_cast(s16x8, alv);
#pragma unroll
    for (int ct = 0; ct < 8; ++ct) {
        i32x4 bh = *(const i32x4*)&sB[(ct * 64 + l) * 4];
        i32x4 bl = *(const i32x4*)&sB[2048 + (ct * 64 + l) * 4];
        s16x8 Bh = __builtin_bit_cast(s16x8, bh);
        s16x8 Bl = __builtin_bit_cast(s16x8, bl);
        acc[ct] = __builtin_amdgcn_mfma_f32_16x16x32_bf16(Ah, Bh, acc[ct], 0, 0, 0);
        acc[ct] = __builtin_amdgcn_mfma_f32_16x16x32_bf16(Al, Bh, acc[ct], 0, 0, 0);
        acc[ct] = __builtin_amdgcn_mfma_f32_16x16x32_bf16(Ah, Bl, acc[ct], 0, 0, 0);
    }
}

// ---------------------------------------------------------------- fused GCN2 layer (MFMA)
__global__ __launch_bounds__(256) void gcn_layer(const float* __restrict__ xin,
                                                 float* __restrict__ xout,
                                                 const float* __restrict__ pos,
                                                 const float* __restrict__ W0,
                                                 const float* __restrict__ b0,
                                                 const unsigned* __restrict__ whi,
                                                 const unsigned* __restrict__ wlo,
                                                 const int* __restrict__ nbr,
                                                 float omb, float beta)
{
    __shared__ float sh[64][129];
    __shared__ __align__(16) unsigned sB[4096];
    __shared__ float sW0[512];
    const int t = threadIdx.x;
    const int bid = blockIdx.x;
    const int swz = (bid & 7) * 128 + (bid >> 3);      // XCD-chunked, bijective
    const int node0 = swz * 64;

    if (t < 128) {
        sW0[t] = W0[t]; sW0[128 + t] = W0[128 + t];
        sW0[256 + t] = W0[256 + t]; sW0[384 + t] = b0[t];
    }
    __syncthreads();

    const float4* xin4 = (const float4*)xin;
    for (int u = t; u < 64 * 32; u += 256) {
        int n = u >> 5, qd = u & 31;
        int node = node0 + n;
        float ax = 0.f, ay = 0.f, az = 0.f, aw = 0.f;
        const int* nb = nbr + node * KNN;
#pragma unroll
        for (int k = 0; k < KNN; ++k) {
            float4 v = xin4[nb[k] * 32 + qd];
            ax += v.x; ay += v.y; az += v.z; aw += v.w;
        }
        float px = pos[node * 3 + 0], py = pos[node * 3 + 1], pz = pos[node * 3 + 2];
        int c = qd * 4;
        sh[n][c + 0] = fmaf(0.9f, ax, 0.1f * relu_f(fmaf(pz, sW0[256 + c + 0], fmaf(py, sW0[128 + c + 0], fmaf(px, sW0[c + 0], sW0[384 + c + 0])))));
        sh[n][c + 1] = fmaf(0.9f, ay, 0.1f * relu_f(fmaf(pz, sW0[256 + c + 1], fmaf(py, sW0[128 + c + 1], fmaf(px, sW0[c + 1], sW0[384 + c + 1])))));
        sh[n][c + 2] = fmaf(0.9f, az, 0.1f * relu_f(fmaf(pz, sW0[256 + c + 2], fmaf(py, sW0[128 + c + 2], fmaf(px, sW0[c + 2], sW0[384 + c + 2])))));
        sh[n][c + 3] = fmaf(0.9f, aw, 0.1f * relu_f(fmaf(pz, sW0[256 + c + 3], fmaf(py, sW0[128 + c + 3], fmaf(px, sW0[c + 3], sW0[384 + c + 3])))));
    }

    const int w = t >> 6, l = t & 63, lr = l & 15, lg = l >> 4;
    f32x4 acc[8];
    const f32x4 z4 = { 0.f, 0.f, 0.f, 0.f };
#pragma unroll
    for (int ct = 0; ct < 8; ++ct) acc[ct] = z4;

    for (int kk = 0; kk < 4; ++kk) {
        __syncthreads();
        const uint4* srch = (const uint4*)(whi + kk * 2048);
        const uint4* srcl = (const uint4*)(wlo + kk * 2048);
        uint4* dst = (uint4*)sB;
        dst[t] = srch[t];           dst[256 + t] = srch[256 + t];
        dst[512 + t] = srcl[t];     dst[768 + t] = srcl[256 + t];
        __syncthreads();
        gemm_kk(&sh[w * 16 + lr][kk * 32 + lg * 8], sB, l, acc);
    }

#pragma unroll
    for (int ct = 0; ct < 8; ++ct) {
        int col = ct * 16 + lr;
#pragma unroll
        for (int r = 0; r < 4; ++r) {
            int rw = w * 16 + lg * 4 + r;
            float h = sh[rw][col];
            xout[(size_t)(node0 + rw) * HDIM + col] = relu_f(fmaf(omb, h, beta * acc[ct][r]));
        }
    }
}

// ---------------------------------------------------------------- w1 + max-pool (MFMA)
__global__ __launch_bounds__(256) void w1pool_kernel(const float* __restrict__ xin,
                                                     const unsigned* __restrict__ whi,
                                                     const unsigned* __restrict__ wlo,
                                                     const float* __restrict__ b1,
                                                     unsigned int* __restrict__ pool)
{
    __shared__ float sh[64][129];
    __shared__ __align__(16) unsigned sB[4096];
    __shared__ float smax[16][128];
    const int t = threadIdx.x;
    const int bid = blockIdx.x;
    const int swz = (bid & 7) * 128 + (bid >> 3);
    const int node0 = swz * 64;

    const float4* xin4 = (const float4*)xin;
    for (int u = t; u < 64 * 32; u += 256) {
        int n = u >> 5, qd = u & 31;
        float4 v = xin4[(node0 + n) * 32 + qd];
        int c = qd * 4;
        sh[n][c + 0] = v.x; sh[n][c + 1] = v.y; sh[n][c + 2] = v.z; sh[n][c + 3] = v.w;
    }

    const int w = t >> 6, l = t & 63, lr = l & 15, lg = l >> 4;
    f32x4 acc[8];
    const f32x4 z4 = { 0.f, 0.f, 0.f, 0.f };
#pragma unroll
    for (int ct = 0; ct < 8; ++ct) acc[ct] = z4;

    for (int kk = 0; kk < 4; ++kk) {
        __syncthreads();
        const uint4* srch = (const uint4*)(whi + kk * 2048);
        const uint4* srcl = (const uint4*)(wlo + kk * 2048);
        uint4* dst = (uint4*)sB;
        dst[t] = srch[t];           dst[256 + t] = srch[256 + t];
        dst[512 + t] = srcl[t];     dst[768 + t] = srcl[256 + t];
        __syncthreads();
        gemm_kk(&sh[w * 16 + lr][kk * 32 + lg * 8], sB, l, acc);
    }

#pragma unroll
    for (int ct = 0; ct < 8; ++ct) {
        int col = ct * 16 + lr;
        float m = fmaxf(fmaxf(acc[ct][0], acc[ct][1]), fmaxf(acc[ct][2], acc[ct][3]));
        smax[w * 4 + lg][col] = m + b1[col];
    }
    __syncthreads();
    if (t < 128) {
        float m = smax[0][t];
#pragma unroll
        for (int r = 1; r < 16; ++r) m = fmaxf(m, smax[r][t]);
        unsigned int u = __float_as_uint(m);
        unsigned int key = (u & 0x80000000u) ? ~u : (u | 0x80000000u);
        atomicMax(&pool[(node0 >> 12) * HDIM + t], key);
    }
}

// ---------------------------------------------------------------- MLP head (1 block)
__global__ __launch_bounds__(256) void head_kernel(const unsigned int* __restrict__ pool,
                                                   const float* __restrict__ Wm1, const float* __restrict__ bm1,
                                                   const float* __restrict__ g1,  const float* __restrict__ be1,
                                                   const float* __restrict__ Wm2, const float* __restrict__ bm2,
                                                   const float* __restrict__ g2,  const float* __restrict__ be2,
                                                   const float* __restrict__ Wout,const float* __restrict__ bout,
                                                   float* __restrict__ out)
{
    __shared__ float sA[16][128];
    __shared__ float sB2[16][128];
    __shared__ float sL[16][10];
    const int t = threadIdx.x;
    for (int u = t; u < 2048; u += 256) {
        unsigned int k = pool[u];
        unsigned int orig = (k & 0x80000000u) ? (k ^ 0x80000000u) : ~k;
        sA[u >> 7][u & 127] = __uint_as_float(orig);
    }
    __syncthreads();

    if (t < 128) {
        float y[16];
#pragma unroll
        for (int b = 0; b < 16; ++b) y[b] = bm1[t];
        for (int i = 0; i < 128; ++i) {
            float w = Wm1[i * 128 + t];
#pragma unroll
            for (int b = 0; b < 16; ++b) y[b] = fmaf(sA[b][i], w, y[b]);
        }
        float mu = 0.f;
#pragma unroll
        for (int b = 0; b < 16; ++b) mu += y[b];
        mu *= (1.f / 16.f);
        float var = 0.f;
#pragma unroll
        for (int b = 0; b < 16; ++b) { float d = y[b] - mu; var = fmaf(d, d, var); }
        var *= (1.f / 16.f);
        float sc = g1[t] / sqrtf(var + 1e-5f);
        float sb = be1[t];
#pragma unroll
        for (int b = 0; b < 16; ++b) sB2[b][t] = relu_f((y[b] - mu) * sc + sb);
    }
    __syncthreads();

    if (t < 128) {
        float y[16];
#pragma unroll
        for (int b = 0; b < 16; ++b) y[b] = bm2[t];
        for (int i = 0; i < 128; ++i) {
            float w = Wm2[i * 128 + t];
#pragma unroll
            for (int b = 0; b < 16; ++b) y[b] = fmaf(sB2[b][i], w, y[b]);
        }
        float mu = 0.f;
#pragma unroll
        for (int b = 0; b < 16; ++b) mu += y[b];
        mu *= (1.f / 16.f);
        float var = 0.f;
#pragma unroll
        for (int b = 0; b < 16; ++b) { float d = y[b] - mu; var = fmaf(d, d, var); }
        var *= (1.f / 16.f);
        float sc = g2[t] / sqrtf(var + 1e-5f);
        float sb = be2[t];
#pragma unroll
        for (int b = 0; b < 16; ++b) sA[b][t] = relu_f((y[b] - mu) * sc + sb);
    }
    __syncthreads();

    if (t < 160) {
        int b = t / 10, o = t % 10;
        float a = bout[o];
        for (int i = 0; i < 128; ++i) a = fmaf(sA[b][i], Wout[i * 10 + o], a);
        sL[b][o] = a;
    }
    __syncthreads();

    if (t < 16) {
        float m = sL[t][0];
#pragma unroll
        for (int o = 1; o < 10; ++o) m = fmaxf(m, sL[t][o]);
        float s = 0.f;
#pragma unroll
        for (int o = 0; o < 10; ++o) s += expf(sL[t][o] - m);
        float ls = logf(s);
#pragma unroll
        for (int o = 0; o < 10; ++o) out[t * 10 + o] = sL[t][o] - m - ls;
    }
}

// ----------------------------------------------------------------
extern "C" void kernel_launch(void* const* d_in, const int* in_sizes, int n_in,
                              void* d_out, int out_size, void* d_ws, size_t ws_size,
                              hipStream_t stream)
{
    const float* pos = (const float*)d_in[0];
    const float* W0  = (const float*)d_in[1];
    const float* b0  = (const float*)d_in[2];
    const float* Wc  = (const float*)d_in[3];
    const float* W1  = (const float*)d_in[4];
    const float* b1  = (const float*)d_in[5];
    const float* Wm1 = (const float*)d_in[6];
    const float* bm1 = (const float*)d_in[7];
    const float* g1  = (const float*)d_in[8];
    const float* be1 = (const float*)d_in[9];
    const float* Wm2 = (const float*)d_in[10];
    const float* bm2 = (const float*)d_in[11];
    const float* g2  = (const float*)d_in[12];
    const float* be2 = (const float*)d_in[13];
    const float* Wout= (const float*)d_in[14];
    const float* bout= (const float*)d_in[15];
    float* out = (float*)d_out;

    char* ws = (char*)d_ws;
    float*        xA   = (float*)ws;                       // 33,554,432 B
    float*        xB   = (float*)(ws + 33554432);          // 33,554,432 B
    int*          nbr  = (int*)(ws + 67108864);            //  2,621,440 B
    unsigned int* pool = (unsigned int*)(ws + 69730304);   //      8,192 B
    unsigned*     whi  = (unsigned*)(ws + 69738496);       //    163,840 B
    unsigned*     wlo  = (unsigned*)(ws + 69902336);       //    163,840 B
    // KNN hit buffer: 16*4096*8*12*8 = 50,331,648 B, aliases xA+xB (dead
    // before x0/gcn write them).
    uint2* pdi = (uint2*)ws;

    wprep<<<5, 256, 0, stream>>>(Wc, W1, whi, wlo);
    knn_part<<<2048, 256, 0, stream>>>(pos, pdi);
    knn_merge<<<256, 256, 0, stream>>>(pdi, nbr);
    x0_kernel<<<8192, 256, 0, stream>>>(pos, W0, b0, xA);

    const float betas[4] = { 0.40546510810816438f, 0.22314355131420976f,
                             0.15415067982725836f, 0.11778303565638346f };
    gcn_layer<<<1024, 256, 0, stream>>>(xA, xB, pos, W0, b0, whi + 0 * 8192, wlo + 0 * 8192, nbr, 1.f - betas[0], betas[0]);
    gcn_layer<<<1024, 256, 0, stream>>>(xB, xA, pos, W0, b0, whi + 1 * 8192, wlo + 1 * 8192, nbr, 1.f - betas[1], betas[1]);
    gcn_layer<<<1024, 256, 0, stream>>>(xA, xB, pos, W0, b0, whi + 2 * 8192, wlo + 2 * 8192, nbr, 1.f - betas[2], betas[2]);
    gcn_layer<<<1024, 256, 0, stream>>>(xB, xA, pos, W0, b0, whi + 3 * 8192, wlo + 3 * 8192, nbr, 1.f - betas[3], betas[3]);

    hipMemsetAsync(pool, 0, 16 * HDIM * sizeof(unsigned int), stream);
    w1pool_kernel<<<1024, 256, 0, stream>>>(xA, whi + 4 * 8192, wlo + 4 * 8192, b1, pool);
    head_kernel<<<1, 256, 0, stream>>>(pool, Wm1, bm1, g1, be1, Wm2, bm2, g2, be2, Wout, bout, out);
}